// Round 1
// baseline (266.141 us; speedup 1.0000x reference)
//
#include <hip/hip_runtime.h>
#include <math.h>

#define APM   32
#define NMOL  256
#define FEAT  100
#define NPAD  112
#define KPAD  128
#define LAYERS 4
#define NTHREADS 1024
#define NWAVES   16

typedef _Float16 f16x8 __attribute__((ext_vector_type(8)));
typedef float    f32x4 __attribute__((ext_vector_type(4)));

// per-layer f16 frag-weight block layout in ws (element offsets)
#define L1F_OFF 0        // lin1f  14336
#define W1F_OFF 14336    // W1f    3584
#define W2F_OFF 17920    // W2f    14336
#define L2F_OFF 32256    // lin2f  14336
#define LVF_OFF 46592    // linf   14336
#define LWTOT 60928      // per layer
#define WTOTAL  (4*LWTOT) // 243712

__device__ __forceinline__ float sspf(float x){
  // shifted softplus: log(1+exp(x)) - log(2)
  return fmaxf(x, 0.0f) + __logf(1.0f + __expf(-fabsf(x))) - 0.69314718056f;
}

// ---------------------------------------------------------------------------
// One-time weight conversion into f16 MFMA B-fragment order:
//   Bf[((kc*7+nt)*64 + lane)*8 + j] = W[k][f],  k = kc*32+(lane>>4)*8+j,
//   f = nt*16+(lane&15); zero outside (Kdim, 100). Validated layout (R3).
// ---------------------------------------------------------------------------
__global__ __launch_bounds__(256) void prep_weights(
    const float* __restrict__ mlp_w1, const float* __restrict__ mlp_w2,
    const float* __restrict__ lin1_w, const float* __restrict__ lin2_w,
    const float* __restrict__ lin_w,  _Float16* __restrict__ out)
{
  int gid = blockIdx.x*256 + threadIdx.x;      // < 243712 exactly
  int l = gid / LWTOT;
  int r = gid - l*LWTOT;
  const float* W; int Kdim; int e;
  if (r < 14336)      { W = lin1_w + l*10000; Kdim = 100; e = r; }
  else if (r < 17920) { W = mlp_w1 + l*2500;  Kdim = 25;  e = r - 14336; }
  else if (r < 32256) { W = mlp_w2 + l*10000; Kdim = 100; e = r - 17920; }
  else if (r < 46592) { W = lin2_w + l*10000; Kdim = 100; e = r - 32256; }
  else                { W = lin_w  + l*10000; Kdim = 100; e = r - 46592; }
  int j = e & 7, L = (e >> 3) & 63, tile = e >> 9;
  int kc = tile / 7, nt = tile - kc*7;
  int k = kc*32 + ((L >> 4) << 3) + j;
  int f = nt*16 + (L & 15);
  float v = (k < Kdim && f < FEAT) ? W[k*FEAT + f] : 0.0f;
  out[gid] = (_Float16)v;
}

__device__ __forceinline__ void cpw(_Float16* dst, const _Float16* src, int n16){
  const uint4* s = (const uint4*)src;
  uint4* d = (uint4*)dst;
  for (int i = threadIdx.x; i < n16; i += NTHREADS) d[i] = s[i];
}

// ---------------------------------------------------------------------------
// Whole network per molecule in one block: graph + emb + 4 interaction layers
// + readout. 1024 threads = 16 waves (was 8: 113KB LDS limited residency to
// ONE block/CU, so the (512,2) launch actually ran at 2 waves/SIMD — pipes
// <15% busy by cycle count => latency-bound. 16-wave block doubles TLP at the
// SAME <=128-VGPR budget and halves phase-4 serial depth: 2 atoms/wave).
// MFMA layouts (validated in R3): A: m=lane&15,k=(lane>>4)*8+j ; C/D:
// n=lane&15, m=(lane>>4)*4+r.
// ---------------------------------------------------------------------------
__global__ __launch_bounds__(1024) void schnet_mega(
    const int* __restrict__ z, const float* __restrict__ pos,
    const float* __restrict__ emb, const _Float16* __restrict__ wf,
    const float* __restrict__ mlp_b1, const float* __restrict__ mlp_b2,
    const float* __restrict__ lin2_b, const float* __restrict__ lin_b,
    const float* __restrict__ out_w1, const float* __restrict__ out_b1,
    const float* __restrict__ out_w2, const float* __restrict__ out_b2,
    float* __restrict__ out)
{
  __shared__ __align__(16) _Float16 sWA[28672];     // weight staging (57344 B)
  __shared__ __align__(16) _Float16 sAf[APM*136];   // A-frag f16 buffer (h/agg)
  __shared__ __align__(16) _Float16 sBf[APM*136];   // A-frag f16 buffer (t2)
  __shared__ __align__(16) float    sX1[APM*113];   // x1 fp32 (stride 113)
  __shared__ __align__(16) float    sH [APM*NPAD];  // h state fp32
  __shared__ __align__(16) _Float16 sT[NWAVES][32*40]; // per-wave T chunk
  __shared__ float sD [APM*33];
  __shared__ float sCC[APM*33];
  __shared__ float sB1m[NPAD], sB2m[NPAD], sB2l[NPAD], sBlv[NPAD];
  __shared__ float sPos[APM*3];
  __shared__ float sPart[NWAVES];

  int tid = threadIdx.x, lane = tid & 63, wv = tid >> 6;
  int q = lane >> 4, n = lane & 15;
  int mol = blockIdx.x, mb = mol*APM;

  // ---------------- init ----------------
  if (tid < 96) sPos[tid] = pos[mb*3 + tid];
  if (tid >= 96 && tid < 144){                 // zero bias pads 100..111
    int w = (tid-96)/12, i = 100 + (tid-96)%12;
    (w==0 ? sB1m : w==1 ? sB2m : w==2 ? sB2l : sBlv)[i] = 0.0f;
  }
  if (tid < 512){                              // zero sBf k-pad cols 112..127
    int r0 = tid >> 4, c0 = 112 + (tid & 15);
    sBf[r0*136 + c0] = (_Float16)0.0f;
  }
  for (int i = tid; i < APM*NPAD; i += NTHREADS){ // h init from embedding
    int r = i/NPAD, c = i - r*NPAD;
    sH[i] = (c < FEAT) ? emb[z[mb+r]*FEAT + c] : 0.0f;
  }
  __syncthreads();
  for (int p = tid; p < APM*APM; p += NTHREADS){  // distances + raw cutoff
    int i = p >> 5, j = p & 31;
    float dx = sPos[i*3+0]-sPos[j*3+0];
    float dy = sPos[i*3+1]-sPos[j*3+1];
    float dz = sPos[i*3+2]-sPos[j*3+2];
    float d2 = dx*dx + dy*dy + dz*dz;
    float d = (d2 > 36.0f) ? 6.0f : sqrtf(d2);
    sD[i*33+j]  = d;
    sCC[i*33+j] = 0.5f*(__cosf(d*0.52359877559f) + 1.0f);
  }
  __syncthreads();
  if (tid < APM){                              // drop self + 3 farthest: cc=0
    float dd[32];
    #pragma unroll
    for (int j = 0; j < 32; j++) dd[j] = sD[tid*33+j];
    dd[tid] = 1e30f;
    unsigned dropped = 0u;
    for (int rr = 0; rr < 4; rr++){
      float mx = -1.0f; int mj = 0;
      #pragma unroll
      for (int j = 0; j < 32; j++){
        bool ok = !((dropped>>j)&1u) && (dd[j] > mx);
        mx = ok ? dd[j] : mx;  mj = ok ? j : mj;
      }
      dropped |= 1u << mj;
    }
    #pragma unroll
    for (int j = 0; j < 32; j++)
      if ((dropped>>j)&1u) sCC[tid*33+j] = 0.0f;
  }
  __syncthreads();

  // ---------------- interaction layers ----------------
  for (int l = 0; l < LAYERS; l++){
    const _Float16* wl = wf + l*LWTOT;
    // stage lin1f + biases; cvt sH -> sAf (f16 A-frag rows, k-pad zeros)
    cpw(sWA, wl + L1F_OFF, 14336/8);
    if (tid < 400){
      int w = tid/100, i = tid - w*100;
      float v = (w==0 ? mlp_b1 : w==1 ? mlp_b2 : w==2 ? lin2_b : lin_b)[l*FEAT + i];
      (w==0 ? sB1m : w==1 ? sB2m : w==2 ? sB2l : sBlv)[i] = v;
    }
    for (int i = tid; i < APM*KPAD; i += NTHREADS){
      int r = i >> 7, c = i & 127;
      sAf[r*136+c] = (c < NPAD) ? (_Float16)sH[r*NPAD+c] : (_Float16)0.0f;
    }
    __syncthreads();
    // ---- x1 = h @ lin1 -> sX1 fp32 ----
    for (int tau = wv; tau < 14; tau += NWAVES){
      int mt = tau/7, nt = tau - mt*7;
      f32x4 acc = {0.0f,0.0f,0.0f,0.0f};
      #pragma unroll
      for (int kc = 0; kc < 4; kc++){
        f16x8 a = *(const f16x8*)&sAf[(mt*16+n)*136 + kc*32 + q*8];
        f16x8 b = *(const f16x8*)&sWA[((kc*7+nt)*64 + lane)*8];
        acc = __builtin_amdgcn_mfma_f32_16x16x32_f16(a, b, acc, 0, 0, 0);
      }
      #pragma unroll
      for (int r = 0; r < 4; r++)
        sX1[(mt*16+q*4+r)*113 + nt*16+n] = acc[r];
    }
    __syncthreads();
    cpw(sWA, wl + W1F_OFF, (3584+14336)/8);   // W1f @0, W2f @3584 (contiguous)
    __syncthreads();
    // ---- edge MLP + CFConv agg: wave handles atoms wv*2..wv*2+1 ----
    {
      _Float16* myT = sT[wv];
      #pragma unroll 1
      for (int t = 0; t < 2; t++){
        int a = wv*2 + t;
        f16x8 eaA[2];                          // gaussian A-frags
        #pragma unroll
        for (int mt = 0; mt < 2; mt++){
          float d = sD[a*33 + mt*16 + n];
          #pragma unroll
          for (int j = 0; j < 8; j++){
            int g = q*8 + j;
            float dd2 = d - 0.25f*(float)g;
            float v = (g < 25) ? __expf(-8.0f*dd2*dd2) : 0.0f;
            eaA[mt][j] = (_Float16)v;
          }
        }
        f32x4 acc2[2][7];
        #pragma unroll
        for (int mt = 0; mt < 2; mt++)
          #pragma unroll
          for (int nt = 0; nt < 7; nt++)
            acc2[mt][nt] = (f32x4){0.0f,0.0f,0.0f,0.0f};
        #pragma unroll 1
        for (int kc = 0; kc < 4; kc++){
          #pragma unroll
          for (int hh = 0; hh < 2; hh++){
            int nt1 = kc*2 + hh;
            if (nt1 < 7){
              f16x8 bf = *(const f16x8*)&sWA[(nt1*64 + lane)*8];
              float bb = sB1m[nt1*16 + n];
              #pragma unroll
              for (int mt = 0; mt < 2; mt++){
                f32x4 c = __builtin_amdgcn_mfma_f32_16x16x32_f16(eaA[mt], bf,
                            (f32x4){0.0f,0.0f,0.0f,0.0f}, 0, 0, 0);
                #pragma unroll
                for (int r = 0; r < 4; r++)
                  myT[(mt*16+q*4+r)*40 + hh*16 + n] = (_Float16)sspf(c[r] + bb);
              }
            } else {  // kc==3,hh==1: zero T pad cols 16..31 of this chunk
              int row = lane & 31, half = lane >> 5;
              *(f16x8*)&myT[row*40 + 16 + half*8] =
                  (f16x8){0,0,0,0,0,0,0,0};
            }
          }
          f16x8 aT[2];
          #pragma unroll
          for (int mt = 0; mt < 2; mt++)
            aT[mt] = *(const f16x8*)&myT[(mt*16+n)*40 + q*8];
          #pragma unroll
          for (int nt = 0; nt < 7; nt++){
            f16x8 bf = *(const f16x8*)&sWA[3584 + ((kc*7+nt)*64 + lane)*8];
            #pragma unroll
            for (int mt = 0; mt < 2; mt++)
              acc2[mt][nt] = __builtin_amdgcn_mfma_f32_16x16x32_f16(
                               aT[mt], bf, acc2[mt][nt], 0, 0, 0);
          }
        }
        // epilogue: Wf=acc+b2, msg = cc*Wf*x1[e], reduce over edges
        float aggv[7];
        #pragma unroll
        for (int nt = 0; nt < 7; nt++) aggv[nt] = 0.0f;
        #pragma unroll
        for (int mt = 0; mt < 2; mt++){
          #pragma unroll
          for (int r = 0; r < 4; r++){
            int e = mt*16 + q*4 + r;
            float cc = sCC[a*33 + e];
            #pragma unroll
            for (int nt = 0; nt < 7; nt++){
              float wfv = acc2[mt][nt][r] + sB2m[nt*16+n];
              aggv[nt] += (cc*wfv) * sX1[e*113 + nt*16+n];
            }
          }
        }
        #pragma unroll
        for (int nt = 0; nt < 7; nt++){
          aggv[nt] += __shfl_xor(aggv[nt], 16);
          aggv[nt] += __shfl_xor(aggv[nt], 32);
        }
        if (lane < 16){
          #pragma unroll
          for (int nt = 0; nt < 7; nt++)
            sAf[a*136 + nt*16 + lane] = (_Float16)aggv[nt];
          sAf[a*136 + 112 + lane] = (_Float16)0.0f;   // k-pad for next GEMM
        }
      }
    }
    __syncthreads();
    // stage lin2f + linf together (contiguous in prepped buffer) -> one
    // barrier pair instead of two per layer
    cpw(sWA, wl + L2F_OFF, (14336+14336)/8);
    __syncthreads();
    // ---- t2 = ssp(agg @ lin2 + b2l) -> sBf f16 ----
    for (int tau = wv; tau < 14; tau += NWAVES){
      int mt = tau/7, nt = tau - mt*7;
      f32x4 acc = {0.0f,0.0f,0.0f,0.0f};
      #pragma unroll
      for (int kc = 0; kc < 4; kc++){
        f16x8 a = *(const f16x8*)&sAf[(mt*16+n)*136 + kc*32 + q*8];
        f16x8 b = *(const f16x8*)&sWA[((kc*7+nt)*64 + lane)*8];
        acc = __builtin_amdgcn_mfma_f32_16x16x32_f16(a, b, acc, 0, 0, 0);
      }
      float bb = sB2l[nt*16+n];
      #pragma unroll
      for (int r = 0; r < 4; r++)
        sBf[(mt*16+q*4+r)*136 + nt*16+n] = (_Float16)sspf(acc[r] + bb);
    }
    __syncthreads();
    // ---- v = t2 @ lin + bl ; h += v  (linf staged at sWA+14336) ----
    for (int tau = wv; tau < 14; tau += NWAVES){
      int mt = tau/7, nt = tau - mt*7;
      f32x4 acc = {0.0f,0.0f,0.0f,0.0f};
      #pragma unroll
      for (int kc = 0; kc < 4; kc++){
        f16x8 a = *(const f16x8*)&sBf[(mt*16+n)*136 + kc*32 + q*8];
        f16x8 b = *(const f16x8*)&sWA[14336 + ((kc*7+nt)*64 + lane)*8];
        acc = __builtin_amdgcn_mfma_f32_16x16x32_f16(a, b, acc, 0, 0, 0);
      }
      int f = nt*16 + n;
      if (f < FEAT){
        float bb = sBlv[f];
        #pragma unroll
        for (int r = 0; r < 4; r++)
          sH[(mt*16+q*4+r)*NPAD + f] += acc[r] + bb;
      }
    }
    __syncthreads();
  }

  // ---------------- readout ----------------
  float* rw = (float*)sWA;                     // out_w1 [100][50] fp32
  for (int i = tid; i < 5000; i += NTHREADS) rw[i] = out_w1[i];
  if (tid < 50){ sB1m[tid] = out_b1[tid]; sB2m[tid] = out_w2[tid]; }
  __syncthreads();
  float ob2 = out_b2[0];
  float partial = 0.0f;
  for (int t = 0; t < 2; t++){
    int a = wv*2 + t;
    float u = 0.0f;
    if (lane < 50){
      u = sB1m[lane];
      #pragma unroll 4
      for (int c = 0; c < FEAT; c++)
        u += sH[a*NPAD + c] * rw[c*50 + lane];
      u = sspf(u) * sB2m[lane];
    }
    #pragma unroll
    for (int s = 1; s < 64; s <<= 1) u += __shfl_xor(u, s);
    partial += u + ob2;
  }
  if (lane == 0) sPart[wv] = partial;
  __syncthreads();
  if (tid == 0){
    float s = 0.0f;
    #pragma unroll
    for (int i = 0; i < NWAVES; i++) s += sPart[i];
    out[mol] = s;
  }
}

extern "C" void kernel_launch(void* const* d_in, const int* in_sizes, int n_in,
                              void* d_out, int out_size, void* d_ws, size_t ws_size,
                              hipStream_t stream)
{
  const int*   z      = (const int*)  d_in[0];
  const float* pos    = (const float*)d_in[1];
  /* d_in[2] = ptr: molecules are fixed 32-atom blocks; unused */
  const float* emb    = (const float*)d_in[3];
  const float* mlp_w1 = (const float*)d_in[4];
  const float* mlp_b1 = (const float*)d_in[5];
  const float* mlp_w2 = (const float*)d_in[6];
  const float* mlp_b2 = (const float*)d_in[7];
  const float* lin1_w = (const float*)d_in[8];
  const float* lin2_w = (const float*)d_in[9];
  const float* lin2_b = (const float*)d_in[10];
  const float* lin_w  = (const float*)d_in[11];
  const float* lin_b  = (const float*)d_in[12];
  const float* out_w1 = (const float*)d_in[13];
  const float* out_b1 = (const float*)d_in[14];
  const float* out_w2 = (const float*)d_in[15];
  const float* out_b2 = (const float*)d_in[16];

  _Float16* wfrag = (_Float16*)d_ws;           // 243712 f16 = 487 KB

  prep_weights<<<WTOTAL/256, 256, 0, stream>>>(mlp_w1, mlp_w2, lin1_w,
                                               lin2_w, lin_w, wfrag);
  schnet_mega<<<NMOL, NTHREADS, 0, stream>>>(z, pos, emb, wfrag,
      mlp_b1, mlp_b2, lin2_b, lin_b,
      out_w1, out_b1, out_w2, out_b2, (float*)d_out);
}

// Round 2
// 263.863 us; speedup vs baseline: 1.0086x; 1.0086x over previous
//
#include <hip/hip_runtime.h>
#include <math.h>

#define APM   32
#define NMOL  256
#define FEAT  100
#define NPAD  112
#define KPAD  128
#define LAYERS 4
#define NTHREADS 1024
#define NWAVES   16

typedef _Float16 f16x8 __attribute__((ext_vector_type(8)));
typedef float    f32x4 __attribute__((ext_vector_type(4)));

// per-layer f16 frag-weight block layout in ws (element offsets)
#define L1F_OFF 0        // lin1f  14336
#define W1F_OFF 14336    // W1f    3584
#define W2F_OFF 17920    // W2f    14336
#define L2F_OFF 32256    // lin2f  14336
#define LVF_OFF 46592    // linf   14336
#define LWTOT 60928      // per layer
#define WTOTAL  (4*LWTOT) // 243712

__device__ __forceinline__ float sspf(float x){
  // shifted softplus: log(1+exp(x)) - log(2)
  return fmaxf(x, 0.0f) + __logf(1.0f + __expf(-fabsf(x))) - 0.69314718056f;
}

// ---------------------------------------------------------------------------
// One-time weight conversion into f16 MFMA B-fragment order:
//   Bf[((kc*7+nt)*64 + lane)*8 + j] = W[k][f],  k = kc*32+(lane>>4)*8+j,
//   f = nt*16+(lane&15); zero outside (Kdim, 100). Validated layout (R3).
// ---------------------------------------------------------------------------
__global__ __launch_bounds__(256) void prep_weights(
    const float* __restrict__ mlp_w1, const float* __restrict__ mlp_w2,
    const float* __restrict__ lin1_w, const float* __restrict__ lin2_w,
    const float* __restrict__ lin_w,  _Float16* __restrict__ out)
{
  int gid = blockIdx.x*256 + threadIdx.x;      // < 243712 exactly
  int l = gid / LWTOT;
  int r = gid - l*LWTOT;
  const float* W; int Kdim; int e;
  if (r < 14336)      { W = lin1_w + l*10000; Kdim = 100; e = r; }
  else if (r < 17920) { W = mlp_w1 + l*2500;  Kdim = 25;  e = r - 14336; }
  else if (r < 32256) { W = mlp_w2 + l*10000; Kdim = 100; e = r - 17920; }
  else if (r < 46592) { W = lin2_w + l*10000; Kdim = 100; e = r - 32256; }
  else                { W = lin_w  + l*10000; Kdim = 100; e = r - 46592; }
  int j = e & 7, L = (e >> 3) & 63, tile = e >> 9;
  int kc = tile / 7, nt = tile - kc*7;
  int k = kc*32 + ((L >> 4) << 3) + j;
  int f = nt*16 + (L & 15);
  float v = (k < Kdim && f < FEAT) ? W[k*FEAT + f] : 0.0f;
  out[gid] = (_Float16)v;
}

__device__ __forceinline__ void cpw(_Float16* dst, const _Float16* src, int n16){
  const uint4* s = (const uint4*)src;
  uint4* d = (uint4*)dst;
  for (int i = threadIdx.x; i < n16; i += NTHREADS) d[i] = s[i];
}

// ---------------------------------------------------------------------------
// Whole network per molecule in one block: graph + emb + 4 interaction layers
// + readout. 1024 threads = 16 waves. LDS 152KB => exactly 1 block/CU, i.e.
// 4 waves/EU — declare that via __launch_bounds__(1024, 4) so the compiler
// gets the full 128-VGPR budget. (R1: without the 2nd arg it capped at 64
// VGPR for a phantom 8-waves/EU target and spilled acc2[] to scratch:
// 385 MB/dispatch HBM traffic, VALUBusy 54%, MfmaUtil 8.6%.)
// MFMA layouts (validated in R3): A: m=lane&15,k=(lane>>4)*8+j ; C/D:
// n=lane&15, m=(lane>>4)*4+r.
// ---------------------------------------------------------------------------
__global__ __launch_bounds__(1024, 4) void schnet_mega(
    const int* __restrict__ z, const float* __restrict__ pos,
    const float* __restrict__ emb, const _Float16* __restrict__ wf,
    const float* __restrict__ mlp_b1, const float* __restrict__ mlp_b2,
    const float* __restrict__ lin2_b, const float* __restrict__ lin_b,
    const float* __restrict__ out_w1, const float* __restrict__ out_b1,
    const float* __restrict__ out_w2, const float* __restrict__ out_b2,
    float* __restrict__ out)
{
  __shared__ __align__(16) _Float16 sWA[28672];     // weight staging (57344 B)
  __shared__ __align__(16) _Float16 sAf[APM*136];   // A-frag f16 buffer (h/agg)
  __shared__ __align__(16) _Float16 sBf[APM*136];   // A-frag f16 buffer (t2)
  __shared__ __align__(16) float    sX1[APM*113];   // x1 fp32 (stride 113)
  __shared__ __align__(16) float    sH [APM*NPAD];  // h state fp32
  __shared__ __align__(16) _Float16 sT[NWAVES][32*40]; // per-wave T chunk
  __shared__ float sD [APM*33];
  __shared__ float sCC[APM*33];
  __shared__ float sB1m[NPAD], sB2m[NPAD], sB2l[NPAD], sBlv[NPAD];
  __shared__ float sPos[APM*3];
  __shared__ float sPart[NWAVES];

  int tid = threadIdx.x, lane = tid & 63, wv = tid >> 6;
  int q = lane >> 4, n = lane & 15;
  int mol = blockIdx.x, mb = mol*APM;

  // ---------------- init ----------------
  if (tid < 96) sPos[tid] = pos[mb*3 + tid];
  if (tid >= 96 && tid < 144){                 // zero bias pads 100..111
    int w = (tid-96)/12, i = 100 + (tid-96)%12;
    (w==0 ? sB1m : w==1 ? sB2m : w==2 ? sB2l : sBlv)[i] = 0.0f;
  }
  if (tid < 512){                              // zero sBf k-pad cols 112..127
    int r0 = tid >> 4, c0 = 112 + (tid & 15);
    sBf[r0*136 + c0] = (_Float16)0.0f;
  }
  for (int i = tid; i < APM*NPAD; i += NTHREADS){ // h init from embedding
    int r = i/NPAD, c = i - r*NPAD;
    sH[i] = (c < FEAT) ? emb[z[mb+r]*FEAT + c] : 0.0f;
  }
  __syncthreads();
  for (int p = tid; p < APM*APM; p += NTHREADS){  // distances + raw cutoff
    int i = p >> 5, j = p & 31;
    float dx = sPos[i*3+0]-sPos[j*3+0];
    float dy = sPos[i*3+1]-sPos[j*3+1];
    float dz = sPos[i*3+2]-sPos[j*3+2];
    float d2 = dx*dx + dy*dy + dz*dz;
    float d = (d2 > 36.0f) ? 6.0f : sqrtf(d2);
    sD[i*33+j]  = d;
    sCC[i*33+j] = 0.5f*(__cosf(d*0.52359877559f) + 1.0f);
  }
  __syncthreads();
  if (tid < APM){                              // drop self + 3 farthest: cc=0
    float dd[32];
    #pragma unroll
    for (int j = 0; j < 32; j++) dd[j] = sD[tid*33+j];
    dd[tid] = 1e30f;
    unsigned dropped = 0u;
    for (int rr = 0; rr < 4; rr++){
      float mx = -1.0f; int mj = 0;
      #pragma unroll
      for (int j = 0; j < 32; j++){
        bool ok = !((dropped>>j)&1u) && (dd[j] > mx);
        mx = ok ? dd[j] : mx;  mj = ok ? j : mj;
      }
      dropped |= 1u << mj;
    }
    #pragma unroll
    for (int j = 0; j < 32; j++)
      if ((dropped>>j)&1u) sCC[tid*33+j] = 0.0f;
  }
  __syncthreads();

  // ---------------- interaction layers ----------------
  for (int l = 0; l < LAYERS; l++){
    const _Float16* wl = wf + l*LWTOT;
    // stage lin1f + biases; cvt sH -> sAf (f16 A-frag rows, k-pad zeros)
    cpw(sWA, wl + L1F_OFF, 14336/8);
    if (tid < 400){
      int w = tid/100, i = tid - w*100;
      float v = (w==0 ? mlp_b1 : w==1 ? mlp_b2 : w==2 ? lin2_b : lin_b)[l*FEAT + i];
      (w==0 ? sB1m : w==1 ? sB2m : w==2 ? sB2l : sBlv)[i] = v;
    }
    for (int i = tid; i < APM*KPAD; i += NTHREADS){
      int r = i >> 7, c = i & 127;
      sAf[r*136+c] = (c < NPAD) ? (_Float16)sH[r*NPAD+c] : (_Float16)0.0f;
    }
    __syncthreads();
    // ---- x1 = h @ lin1 -> sX1 fp32 ----
    for (int tau = wv; tau < 14; tau += NWAVES){
      int mt = tau/7, nt = tau - mt*7;
      f32x4 acc = {0.0f,0.0f,0.0f,0.0f};
      #pragma unroll
      for (int kc = 0; kc < 4; kc++){
        f16x8 a = *(const f16x8*)&sAf[(mt*16+n)*136 + kc*32 + q*8];
        f16x8 b = *(const f16x8*)&sWA[((kc*7+nt)*64 + lane)*8];
        acc = __builtin_amdgcn_mfma_f32_16x16x32_f16(a, b, acc, 0, 0, 0);
      }
      #pragma unroll
      for (int r = 0; r < 4; r++)
        sX1[(mt*16+q*4+r)*113 + nt*16+n] = acc[r];
    }
    __syncthreads();
    cpw(sWA, wl + W1F_OFF, (3584+14336)/8);   // W1f @0, W2f @3584 (contiguous)
    __syncthreads();
    // ---- edge MLP + CFConv agg: wave handles atoms wv*2..wv*2+1 ----
    {
      _Float16* myT = sT[wv];
      #pragma unroll 1
      for (int t = 0; t < 2; t++){
        int a = wv*2 + t;
        f16x8 eaA[2];                          // gaussian A-frags
        #pragma unroll
        for (int mt = 0; mt < 2; mt++){
          float d = sD[a*33 + mt*16 + n];
          #pragma unroll
          for (int j = 0; j < 8; j++){
            int g = q*8 + j;
            float dd2 = d - 0.25f*(float)g;
            float v = (g < 25) ? __expf(-8.0f*dd2*dd2) : 0.0f;
            eaA[mt][j] = (_Float16)v;
          }
        }
        f32x4 acc2[2][7];
        #pragma unroll
        for (int mt = 0; mt < 2; mt++)
          #pragma unroll
          for (int nt = 0; nt < 7; nt++)
            acc2[mt][nt] = (f32x4){0.0f,0.0f,0.0f,0.0f};
        #pragma unroll 1
        for (int kc = 0; kc < 4; kc++){
          #pragma unroll
          for (int hh = 0; hh < 2; hh++){
            int nt1 = kc*2 + hh;
            if (nt1 < 7){
              f16x8 bf = *(const f16x8*)&sWA[(nt1*64 + lane)*8];
              float bb = sB1m[nt1*16 + n];
              #pragma unroll
              for (int mt = 0; mt < 2; mt++){
                f32x4 c = __builtin_amdgcn_mfma_f32_16x16x32_f16(eaA[mt], bf,
                            (f32x4){0.0f,0.0f,0.0f,0.0f}, 0, 0, 0);
                #pragma unroll
                for (int r = 0; r < 4; r++)
                  myT[(mt*16+q*4+r)*40 + hh*16 + n] = (_Float16)sspf(c[r] + bb);
              }
            } else {  // kc==3,hh==1: zero T pad cols 16..31 of this chunk
              int row = lane & 31, half = lane >> 5;
              *(f16x8*)&myT[row*40 + 16 + half*8] =
                  (f16x8){0,0,0,0,0,0,0,0};
            }
          }
          f16x8 aT[2];
          #pragma unroll
          for (int mt = 0; mt < 2; mt++)
            aT[mt] = *(const f16x8*)&myT[(mt*16+n)*40 + q*8];
          #pragma unroll
          for (int nt = 0; nt < 7; nt++){
            f16x8 bf = *(const f16x8*)&sWA[3584 + ((kc*7+nt)*64 + lane)*8];
            #pragma unroll
            for (int mt = 0; mt < 2; mt++)
              acc2[mt][nt] = __builtin_amdgcn_mfma_f32_16x16x32_f16(
                               aT[mt], bf, acc2[mt][nt], 0, 0, 0);
          }
        }
        // epilogue: Wf=acc+b2, msg = cc*Wf*x1[e], reduce over edges
        float aggv[7];
        #pragma unroll
        for (int nt = 0; nt < 7; nt++) aggv[nt] = 0.0f;
        #pragma unroll
        for (int mt = 0; mt < 2; mt++){
          #pragma unroll
          for (int r = 0; r < 4; r++){
            int e = mt*16 + q*4 + r;
            float cc = sCC[a*33 + e];
            #pragma unroll
            for (int nt = 0; nt < 7; nt++){
              float wfv = acc2[mt][nt][r] + sB2m[nt*16+n];
              aggv[nt] += (cc*wfv) * sX1[e*113 + nt*16+n];
            }
          }
        }
        #pragma unroll
        for (int nt = 0; nt < 7; nt++){
          aggv[nt] += __shfl_xor(aggv[nt], 16);
          aggv[nt] += __shfl_xor(aggv[nt], 32);
        }
        if (lane < 16){
          #pragma unroll
          for (int nt = 0; nt < 7; nt++)
            sAf[a*136 + nt*16 + lane] = (_Float16)aggv[nt];
          sAf[a*136 + 112 + lane] = (_Float16)0.0f;   // k-pad for next GEMM
        }
      }
    }
    __syncthreads();
    // stage lin2f + linf together (contiguous in prepped buffer) -> one
    // barrier pair instead of two per layer
    cpw(sWA, wl + L2F_OFF, (14336+14336)/8);
    __syncthreads();
    // ---- t2 = ssp(agg @ lin2 + b2l) -> sBf f16 ----
    for (int tau = wv; tau < 14; tau += NWAVES){
      int mt = tau/7, nt = tau - mt*7;
      f32x4 acc = {0.0f,0.0f,0.0f,0.0f};
      #pragma unroll
      for (int kc = 0; kc < 4; kc++){
        f16x8 a = *(const f16x8*)&sAf[(mt*16+n)*136 + kc*32 + q*8];
        f16x8 b = *(const f16x8*)&sWA[((kc*7+nt)*64 + lane)*8];
        acc = __builtin_amdgcn_mfma_f32_16x16x32_f16(a, b, acc, 0, 0, 0);
      }
      float bb = sB2l[nt*16+n];
      #pragma unroll
      for (int r = 0; r < 4; r++)
        sBf[(mt*16+q*4+r)*136 + nt*16+n] = (_Float16)sspf(acc[r] + bb);
    }
    __syncthreads();
    // ---- v = t2 @ lin + bl ; h += v  (linf staged at sWA+14336) ----
    for (int tau = wv; tau < 14; tau += NWAVES){
      int mt = tau/7, nt = tau - mt*7;
      f32x4 acc = {0.0f,0.0f,0.0f,0.0f};
      #pragma unroll
      for (int kc = 0; kc < 4; kc++){
        f16x8 a = *(const f16x8*)&sBf[(mt*16+n)*136 + kc*32 + q*8];
        f16x8 b = *(const f16x8*)&sWA[14336 + ((kc*7+nt)*64 + lane)*8];
        acc = __builtin_amdgcn_mfma_f32_16x16x32_f16(a, b, acc, 0, 0, 0);
      }
      int f = nt*16 + n;
      if (f < FEAT){
        float bb = sBlv[f];
        #pragma unroll
        for (int r = 0; r < 4; r++)
          sH[(mt*16+q*4+r)*NPAD + f] += acc[r] + bb;
      }
    }
    __syncthreads();
  }

  // ---------------- readout ----------------
  float* rw = (float*)sWA;                     // out_w1 [100][50] fp32
  for (int i = tid; i < 5000; i += NTHREADS) rw[i] = out_w1[i];
  if (tid < 50){ sB1m[tid] = out_b1[tid]; sB2m[tid] = out_w2[tid]; }
  __syncthreads();
  float ob2 = out_b2[0];
  float partial = 0.0f;
  for (int t = 0; t < 2; t++){
    int a = wv*2 + t;
    float u = 0.0f;
    if (lane < 50){
      u = sB1m[lane];
      #pragma unroll 4
      for (int c = 0; c < FEAT; c++)
        u += sH[a*NPAD + c] * rw[c*50 + lane];
      u = sspf(u) * sB2m[lane];
    }
    #pragma unroll
    for (int s = 1; s < 64; s <<= 1) u += __shfl_xor(u, s);
    partial += u + ob2;
  }
  if (lane == 0) sPart[wv] = partial;
  __syncthreads();
  if (tid == 0){
    float s = 0.0f;
    #pragma unroll
    for (int i = 0; i < NWAVES; i++) s += sPart[i];
    out[mol] = s;
  }
}

extern "C" void kernel_launch(void* const* d_in, const int* in_sizes, int n_in,
                              void* d_out, int out_size, void* d_ws, size_t ws_size,
                              hipStream_t stream)
{
  const int*   z      = (const int*)  d_in[0];
  const float* pos    = (const float*)d_in[1];
  /* d_in[2] = ptr: molecules are fixed 32-atom blocks; unused */
  const float* emb    = (const float*)d_in[3];
  const float* mlp_w1 = (const float*)d_in[4];
  const float* mlp_b1 = (const float*)d_in[5];
  const float* mlp_w2 = (const float*)d_in[6];
  const float* mlp_b2 = (const float*)d_in[7];
  const float* lin1_w = (const float*)d_in[8];
  const float* lin2_w = (const float*)d_in[9];
  const float* lin2_b = (const float*)d_in[10];
  const float* lin_w  = (const float*)d_in[11];
  const float* lin_b  = (const float*)d_in[12];
  const float* out_w1 = (const float*)d_in[13];
  const float* out_b1 = (const float*)d_in[14];
  const float* out_w2 = (const float*)d_in[15];
  const float* out_b2 = (const float*)d_in[16];

  _Float16* wfrag = (_Float16*)d_ws;           // 243712 f16 = 487 KB

  prep_weights<<<WTOTAL/256, 256, 0, stream>>>(mlp_w1, mlp_w2, lin1_w,
                                               lin2_w, lin_w, wfrag);
  schnet_mega<<<NMOL, NTHREADS, 0, stream>>>(z, pos, emb, wfrag,
      mlp_b1, mlp_b2, lin2_b, lin_b,
      out_w1, out_b1, out_w2, out_b2, (float*)d_out);
}

// Round 3
// 260.993 us; speedup vs baseline: 1.0197x; 1.0110x over previous
//
#include <hip/hip_runtime.h>
#include <math.h>

#define APM   32
#define NMOL  256
#define FEAT  100
#define NPAD  112
#define KPAD  128
#define LAYERS 4
#define NTHREADS 1024
#define NWAVES   16

typedef _Float16 f16x8 __attribute__((ext_vector_type(8)));
typedef float    f32x4 __attribute__((ext_vector_type(4)));

// per-layer f16 frag-weight block layout in ws (element offsets)
#define L1F_OFF 0        // lin1f  14336
#define W1F_OFF 14336    // W1f    3584
#define W2F_OFF 17920    // W2f    14336
#define L2F_OFF 32256    // lin2f  14336
#define LVF_OFF 46592    // linf   14336
#define LWTOT 60928      // per layer
#define WTOTAL  (4*LWTOT) // 243712

__device__ __forceinline__ float sspf(float x){
  // shifted softplus: log(1+exp(x)) - log(2)
  return fmaxf(x, 0.0f) + __logf(1.0f + __expf(-fabsf(x))) - 0.69314718056f;
}

// ---------------------------------------------------------------------------
// One-time weight conversion into f16 MFMA B-fragment order:
//   Bf[((kc*7+nt)*64 + lane)*8 + j] = W[k][f],  k = kc*32+(lane>>4)*8+j,
//   f = nt*16+(lane&15); zero outside (Kdim, 100). Validated layout (R3).
// ---------------------------------------------------------------------------
__global__ __launch_bounds__(256) void prep_weights(
    const float* __restrict__ mlp_w1, const float* __restrict__ mlp_w2,
    const float* __restrict__ lin1_w, const float* __restrict__ lin2_w,
    const float* __restrict__ lin_w,  _Float16* __restrict__ out)
{
  int gid = blockIdx.x*256 + threadIdx.x;      // < 243712 exactly
  int l = gid / LWTOT;
  int r = gid - l*LWTOT;
  const float* W; int Kdim; int e;
  if (r < 14336)      { W = lin1_w + l*10000; Kdim = 100; e = r; }
  else if (r < 17920) { W = mlp_w1 + l*2500;  Kdim = 25;  e = r - 14336; }
  else if (r < 32256) { W = mlp_w2 + l*10000; Kdim = 100; e = r - 17920; }
  else if (r < 46592) { W = lin2_w + l*10000; Kdim = 100; e = r - 32256; }
  else                { W = lin_w  + l*10000; Kdim = 100; e = r - 46592; }
  int j = e & 7, L = (e >> 3) & 63, tile = e >> 9;
  int kc = tile / 7, nt = tile - kc*7;
  int k = kc*32 + ((L >> 4) << 3) + j;
  int f = nt*16 + (L & 15);
  float v = (k < Kdim && f < FEAT) ? W[k*FEAT + f] : 0.0f;
  out[gid] = (_Float16)v;
}

__device__ __forceinline__ void cpw(_Float16* dst, const _Float16* src, int n16){
  const uint4* s = (const uint4*)src;
  uint4* d = (uint4*)dst;
  for (int i = threadIdx.x; i < n16; i += NTHREADS) d[i] = s[i];
}

// ---------------------------------------------------------------------------
// Whole network per molecule in one block: graph + emb + 4 interaction layers
// + readout. 1024 threads = 16 waves. LDS 152KB => exactly 1 block/CU =
// 4 waves/EU. amdgpu_waves_per_eu(4,4): R2 showed __launch_bounds__(1024,4)
// (min-only) leaves the allocator TARGETING 8 waves/EU -> 64 arch VGPRs and
// scratch spills (FETCH 195MB + WRITE 180MB phantom HBM traffic for a kernel
// whose unique data is <2MB). Pinning max=4 hands the allocator the full
// 128-VGPR budget so acc2[2][7]+eaA+aT stay in registers.
// MFMA layouts (validated in R3): A: m=lane&15,k=(lane>>4)*8+j ; C/D:
// n=lane&15, m=(lane>>4)*4+r.
// ---------------------------------------------------------------------------
__global__ __launch_bounds__(1024)
__attribute__((amdgpu_waves_per_eu(4, 4)))
void schnet_mega(
    const int* __restrict__ z, const float* __restrict__ pos,
    const float* __restrict__ emb, const _Float16* __restrict__ wf,
    const float* __restrict__ mlp_b1, const float* __restrict__ mlp_b2,
    const float* __restrict__ lin2_b, const float* __restrict__ lin_b,
    const float* __restrict__ out_w1, const float* __restrict__ out_b1,
    const float* __restrict__ out_w2, const float* __restrict__ out_b2,
    float* __restrict__ out)
{
  __shared__ __align__(16) _Float16 sWA[28672];     // weight staging (57344 B)
  __shared__ __align__(16) _Float16 sAf[APM*136];   // A-frag f16 buffer (h/agg)
  __shared__ __align__(16) _Float16 sBf[APM*136];   // A-frag f16 buffer (t2)
  __shared__ __align__(16) float    sX1[APM*113];   // x1 fp32 (stride 113)
  __shared__ __align__(16) float    sH [APM*NPAD];  // h state fp32
  __shared__ __align__(16) _Float16 sT[NWAVES][32*40]; // per-wave T chunk
  __shared__ float sD [APM*33];
  __shared__ float sCC[APM*33];
  __shared__ float sB1m[NPAD], sB2m[NPAD], sB2l[NPAD], sBlv[NPAD];
  __shared__ float sPos[APM*3];
  __shared__ float sPart[NWAVES];

  int tid = threadIdx.x, lane = tid & 63, wv = tid >> 6;
  int q = lane >> 4, n = lane & 15;
  int mol = blockIdx.x, mb = mol*APM;

  // ---------------- init ----------------
  if (tid < 96) sPos[tid] = pos[mb*3 + tid];
  if (tid >= 96 && tid < 144){                 // zero bias pads 100..111
    int w = (tid-96)/12, i = 100 + (tid-96)%12;
    (w==0 ? sB1m : w==1 ? sB2m : w==2 ? sB2l : sBlv)[i] = 0.0f;
  }
  if (tid < 512){                              // zero sBf k-pad cols 112..127
    int r0 = tid >> 4, c0 = 112 + (tid & 15);
    sBf[r0*136 + c0] = (_Float16)0.0f;
  }
  for (int i = tid; i < APM*NPAD; i += NTHREADS){ // h init from embedding
    int r = i/NPAD, c = i - r*NPAD;
    sH[i] = (c < FEAT) ? emb[z[mb+r]*FEAT + c] : 0.0f;
  }
  __syncthreads();
  for (int p = tid; p < APM*APM; p += NTHREADS){  // distances + raw cutoff
    int i = p >> 5, j = p & 31;
    float dx = sPos[i*3+0]-sPos[j*3+0];
    float dy = sPos[i*3+1]-sPos[j*3+1];
    float dz = sPos[i*3+2]-sPos[j*3+2];
    float d2 = dx*dx + dy*dy + dz*dz;
    float d = (d2 > 36.0f) ? 6.0f : sqrtf(d2);
    sD[i*33+j]  = d;
    sCC[i*33+j] = 0.5f*(__cosf(d*0.52359877559f) + 1.0f);
  }
  __syncthreads();
  if (tid < APM){                              // drop self + 3 farthest: cc=0
    float dd[32];
    #pragma unroll
    for (int j = 0; j < 32; j++) dd[j] = sD[tid*33+j];
    dd[tid] = 1e30f;
    unsigned dropped = 0u;
    for (int rr = 0; rr < 4; rr++){
      float mx = -1.0f; int mj = 0;
      #pragma unroll
      for (int j = 0; j < 32; j++){
        bool ok = !((dropped>>j)&1u) && (dd[j] > mx);
        mx = ok ? dd[j] : mx;  mj = ok ? j : mj;
      }
      dropped |= 1u << mj;
    }
    #pragma unroll
    for (int j = 0; j < 32; j++)
      if ((dropped>>j)&1u) sCC[tid*33+j] = 0.0f;
  }
  __syncthreads();

  // ---------------- interaction layers ----------------
  for (int l = 0; l < LAYERS; l++){
    const _Float16* wl = wf + l*LWTOT;
    // stage lin1f + biases; cvt sH -> sAf (f16 A-frag rows, k-pad zeros)
    cpw(sWA, wl + L1F_OFF, 14336/8);
    if (tid < 400){
      int w = tid/100, i = tid - w*100;
      float v = (w==0 ? mlp_b1 : w==1 ? mlp_b2 : w==2 ? lin2_b : lin_b)[l*FEAT + i];
      (w==0 ? sB1m : w==1 ? sB2m : w==2 ? sB2l : sBlv)[i] = v;
    }
    for (int i = tid; i < APM*KPAD; i += NTHREADS){
      int r = i >> 7, c = i & 127;
      sAf[r*136+c] = (c < NPAD) ? (_Float16)sH[r*NPAD+c] : (_Float16)0.0f;
    }
    __syncthreads();
    // ---- x1 = h @ lin1 -> sX1 fp32 ----
    for (int tau = wv; tau < 14; tau += NWAVES){
      int mt = tau/7, nt = tau - mt*7;
      f32x4 acc = {0.0f,0.0f,0.0f,0.0f};
      #pragma unroll
      for (int kc = 0; kc < 4; kc++){
        f16x8 a = *(const f16x8*)&sAf[(mt*16+n)*136 + kc*32 + q*8];
        f16x8 b = *(const f16x8*)&sWA[((kc*7+nt)*64 + lane)*8];
        acc = __builtin_amdgcn_mfma_f32_16x16x32_f16(a, b, acc, 0, 0, 0);
      }
      #pragma unroll
      for (int r = 0; r < 4; r++)
        sX1[(mt*16+q*4+r)*113 + nt*16+n] = acc[r];
    }
    __syncthreads();
    cpw(sWA, wl + W1F_OFF, (3584+14336)/8);   // W1f @0, W2f @3584 (contiguous)
    __syncthreads();
    // ---- edge MLP + CFConv agg: wave handles atoms wv*2..wv*2+1 ----
    {
      _Float16* myT = sT[wv];
      #pragma unroll 1
      for (int t = 0; t < 2; t++){
        int a = wv*2 + t;
        f16x8 eaA[2];                          // gaussian A-frags
        #pragma unroll
        for (int mt = 0; mt < 2; mt++){
          float d = sD[a*33 + mt*16 + n];
          #pragma unroll
          for (int j = 0; j < 8; j++){
            int g = q*8 + j;
            float dd2 = d - 0.25f*(float)g;
            float v = (g < 25) ? __expf(-8.0f*dd2*dd2) : 0.0f;
            eaA[mt][j] = (_Float16)v;
          }
        }
        f32x4 acc2[2][7];
        #pragma unroll
        for (int mt = 0; mt < 2; mt++)
          #pragma unroll
          for (int nt = 0; nt < 7; nt++)
            acc2[mt][nt] = (f32x4){0.0f,0.0f,0.0f,0.0f};
        #pragma unroll 1
        for (int kc = 0; kc < 4; kc++){
          #pragma unroll
          for (int hh = 0; hh < 2; hh++){
            int nt1 = kc*2 + hh;
            if (nt1 < 7){
              f16x8 bf = *(const f16x8*)&sWA[(nt1*64 + lane)*8];
              float bb = sB1m[nt1*16 + n];
              #pragma unroll
              for (int mt = 0; mt < 2; mt++){
                f32x4 c = __builtin_amdgcn_mfma_f32_16x16x32_f16(eaA[mt], bf,
                            (f32x4){0.0f,0.0f,0.0f,0.0f}, 0, 0, 0);
                #pragma unroll
                for (int r = 0; r < 4; r++)
                  myT[(mt*16+q*4+r)*40 + hh*16 + n] = (_Float16)sspf(c[r] + bb);
              }
            } else {  // kc==3,hh==1: zero T pad cols 16..31 of this chunk
              int row = lane & 31, half = lane >> 5;
              *(f16x8*)&myT[row*40 + 16 + half*8] =
                  (f16x8){0,0,0,0,0,0,0,0};
            }
          }
          f16x8 aT[2];
          #pragma unroll
          for (int mt = 0; mt < 2; mt++)
            aT[mt] = *(const f16x8*)&myT[(mt*16+n)*40 + q*8];
          #pragma unroll
          for (int nt = 0; nt < 7; nt++){
            f16x8 bf = *(const f16x8*)&sWA[3584 + ((kc*7+nt)*64 + lane)*8];
            #pragma unroll
            for (int mt = 0; mt < 2; mt++)
              acc2[mt][nt] = __builtin_amdgcn_mfma_f32_16x16x32_f16(
                               aT[mt], bf, acc2[mt][nt], 0, 0, 0);
          }
        }
        // epilogue: Wf=acc+b2, msg = cc*Wf*x1[e], reduce over edges
        float aggv[7];
        #pragma unroll
        for (int nt = 0; nt < 7; nt++) aggv[nt] = 0.0f;
        #pragma unroll
        for (int mt = 0; mt < 2; mt++){
          #pragma unroll
          for (int r = 0; r < 4; r++){
            int e = mt*16 + q*4 + r;
            float cc = sCC[a*33 + e];
            #pragma unroll
            for (int nt = 0; nt < 7; nt++){
              float wfv = acc2[mt][nt][r] + sB2m[nt*16+n];
              aggv[nt] += (cc*wfv) * sX1[e*113 + nt*16+n];
            }
          }
        }
        #pragma unroll
        for (int nt = 0; nt < 7; nt++){
          aggv[nt] += __shfl_xor(aggv[nt], 16);
          aggv[nt] += __shfl_xor(aggv[nt], 32);
        }
        if (lane < 16){
          #pragma unroll
          for (int nt = 0; nt < 7; nt++)
            sAf[a*136 + nt*16 + lane] = (_Float16)aggv[nt];
          sAf[a*136 + 112 + lane] = (_Float16)0.0f;   // k-pad for next GEMM
        }
      }
    }
    __syncthreads();
    // stage lin2f + linf together (contiguous in prepped buffer) -> one
    // barrier pair instead of two per layer
    cpw(sWA, wl + L2F_OFF, (14336+14336)/8);
    __syncthreads();
    // ---- t2 = ssp(agg @ lin2 + b2l) -> sBf f16 ----
    for (int tau = wv; tau < 14; tau += NWAVES){
      int mt = tau/7, nt = tau - mt*7;
      f32x4 acc = {0.0f,0.0f,0.0f,0.0f};
      #pragma unroll
      for (int kc = 0; kc < 4; kc++){
        f16x8 a = *(const f16x8*)&sAf[(mt*16+n)*136 + kc*32 + q*8];
        f16x8 b = *(const f16x8*)&sWA[((kc*7+nt)*64 + lane)*8];
        acc = __builtin_amdgcn_mfma_f32_16x16x32_f16(a, b, acc, 0, 0, 0);
      }
      float bb = sB2l[nt*16+n];
      #pragma unroll
      for (int r = 0; r < 4; r++)
        sBf[(mt*16+q*4+r)*136 + nt*16+n] = (_Float16)sspf(acc[r] + bb);
    }
    __syncthreads();
    // ---- v = t2 @ lin + bl ; h += v  (linf staged at sWA+14336) ----
    for (int tau = wv; tau < 14; tau += NWAVES){
      int mt = tau/7, nt = tau - mt*7;
      f32x4 acc = {0.0f,0.0f,0.0f,0.0f};
      #pragma unroll
      for (int kc = 0; kc < 4; kc++){
        f16x8 a = *(const f16x8*)&sBf[(mt*16+n)*136 + kc*32 + q*8];
        f16x8 b = *(const f16x8*)&sWA[14336 + ((kc*7+nt)*64 + lane)*8];
        acc = __builtin_amdgcn_mfma_f32_16x16x32_f16(a, b, acc, 0, 0, 0);
      }
      int f = nt*16 + n;
      if (f < FEAT){
        float bb = sBlv[f];
        #pragma unroll
        for (int r = 0; r < 4; r++)
          sH[(mt*16+q*4+r)*NPAD + f] += acc[r] + bb;
      }
    }
    __syncthreads();
  }

  // ---------------- readout ----------------
  float* rw = (float*)sWA;                     // out_w1 [100][50] fp32
  for (int i = tid; i < 5000; i += NTHREADS) rw[i] = out_w1[i];
  if (tid < 50){ sB1m[tid] = out_b1[tid]; sB2m[tid] = out_w2[tid]; }
  __syncthreads();
  float ob2 = out_b2[0];
  float partial = 0.0f;
  for (int t = 0; t < 2; t++){
    int a = wv*2 + t;
    float u = 0.0f;
    if (lane < 50){
      u = sB1m[lane];
      #pragma unroll 4
      for (int c = 0; c < FEAT; c++)
        u += sH[a*NPAD + c] * rw[c*50 + lane];
      u = sspf(u) * sB2m[lane];
    }
    #pragma unroll
    for (int s = 1; s < 64; s <<= 1) u += __shfl_xor(u, s);
    partial += u + ob2;
  }
  if (lane == 0) sPart[wv] = partial;
  __syncthreads();
  if (tid == 0){
    float s = 0.0f;
    #pragma unroll
    for (int i = 0; i < NWAVES; i++) s += sPart[i];
    out[mol] = s;
  }
}

extern "C" void kernel_launch(void* const* d_in, const int* in_sizes, int n_in,
                              void* d_out, int out_size, void* d_ws, size_t ws_size,
                              hipStream_t stream)
{
  const int*   z      = (const int*)  d_in[0];
  const float* pos    = (const float*)d_in[1];
  /* d_in[2] = ptr: molecules are fixed 32-atom blocks; unused */
  const float* emb    = (const float*)d_in[3];
  const float* mlp_w1 = (const float*)d_in[4];
  const float* mlp_b1 = (const float*)d_in[5];
  const float* mlp_w2 = (const float*)d_in[6];
  const float* mlp_b2 = (const float*)d_in[7];
  const float* lin1_w = (const float*)d_in[8];
  const float* lin2_w = (const float*)d_in[9];
  const float* lin2_b = (const float*)d_in[10];
  const float* lin_w  = (const float*)d_in[11];
  const float* lin_b  = (const float*)d_in[12];
  const float* out_w1 = (const float*)d_in[13];
  const float* out_b1 = (const float*)d_in[14];
  const float* out_w2 = (const float*)d_in[15];
  const float* out_b2 = (const float*)d_in[16];

  _Float16* wfrag = (_Float16*)d_ws;           // 243712 f16 = 487 KB

  prep_weights<<<WTOTAL/256, 256, 0, stream>>>(mlp_w1, mlp_w2, lin1_w,
                                               lin2_w, lin_w, wfrag);
  schnet_mega<<<NMOL, NTHREADS, 0, stream>>>(z, pos, emb, wfrag,
      mlp_b1, mlp_b2, lin2_b, lin_b,
      out_w1, out_b1, out_w2, out_b2, (float*)d_out);
}

// Round 4
// 221.402 us; speedup vs baseline: 1.2021x; 1.1788x over previous
//
#include <hip/hip_runtime.h>
#include <math.h>

#define APM   32
#define NMOL  256
#define FEAT  100
#define NPAD  112
#define KPAD  128
#define LAYERS 4
#define NTHREADS 1024
#define NWAVES   16

typedef _Float16 f16x8 __attribute__((ext_vector_type(8)));
typedef float    f32x4 __attribute__((ext_vector_type(4)));

// per-layer f16 frag-weight block layout in ws (element offsets)
#define L1F_OFF 0        // lin1f  14336
#define W1F_OFF 14336    // W1f    3584
#define W2F_OFF 17920    // W2f    14336
#define L2F_OFF 32256    // lin2f  14336
#define LVF_OFF 46592    // linf   14336
#define LWTOT 60928      // per layer
#define WTOTAL  (4*LWTOT) // 243712

__device__ __forceinline__ float sspf(float x){
  // shifted softplus: log(1+exp(x)) - log(2)
  return fmaxf(x, 0.0f) + __logf(1.0f + __expf(-fabsf(x))) - 0.69314718056f;
}

// ---------------------------------------------------------------------------
// One-time weight conversion into f16 MFMA B-fragment order:
//   Bf[((kc*7+nt)*64 + lane)*8 + j] = W[k][f],  k = kc*32+(lane>>4)*8+j,
//   f = nt*16+(lane&15); zero outside (Kdim, 100). Validated layout (R3).
// ---------------------------------------------------------------------------
__global__ __launch_bounds__(256) void prep_weights(
    const float* __restrict__ mlp_w1, const float* __restrict__ mlp_w2,
    const float* __restrict__ lin1_w, const float* __restrict__ lin2_w,
    const float* __restrict__ lin_w,  _Float16* __restrict__ out)
{
  int gid = blockIdx.x*256 + threadIdx.x;      // < 243712 exactly
  int l = gid / LWTOT;
  int r = gid - l*LWTOT;
  const float* W; int Kdim; int e;
  if (r < 14336)      { W = lin1_w + l*10000; Kdim = 100; e = r; }
  else if (r < 17920) { W = mlp_w1 + l*2500;  Kdim = 25;  e = r - 14336; }
  else if (r < 32256) { W = mlp_w2 + l*10000; Kdim = 100; e = r - 17920; }
  else if (r < 46592) { W = lin2_w + l*10000; Kdim = 100; e = r - 32256; }
  else                { W = lin_w  + l*10000; Kdim = 100; e = r - 46592; }
  int j = e & 7, L = (e >> 3) & 63, tile = e >> 9;
  int kc = tile / 7, nt = tile - kc*7;
  int k = kc*32 + ((L >> 4) << 3) + j;
  int f = nt*16 + (L & 15);
  float v = (k < Kdim && f < FEAT) ? W[k*FEAT + f] : 0.0f;
  out[gid] = (_Float16)v;
}

__device__ __forceinline__ void cpw(_Float16* dst, const _Float16* src, int n16){
  const uint4* s = (const uint4*)src;
  uint4* d = (uint4*)dst;
  for (int i = threadIdx.x; i < n16; i += NTHREADS) d[i] = s[i];
}

// ---------------------------------------------------------------------------
// Whole network per molecule in one block: graph + emb + 4 interaction layers
// + readout. 1024 threads = 16 waves, 1 block/CU (LDS-capped) = 4 waves/EU =
// 128 unified VGPR+AGPR budget/wave. R1-R3 showed WRITE_SIZE=180MB scratch
// traffic (= 43 f32 spilled/thread/layer): the edge phase held acc2[2][7]
// (56 accums) live across the whole kc loop ON TOP of the T-production
// pipeline -> peak live > 128 -> spill-fill each layer. R4: split the edge
// (reduction) dim into two mt passes of 16 — only acc2[7] (28) live per
// pass, aggv[7] carries the sum. Costs ~35 extra ds_read_b128/atom (W-frag
// re-reads), kills ~360MB of HBM round-trip.
// MFMA layouts (validated in R3): A: m=lane&15,k=(lane>>4)*8+j ; C/D:
// n=lane&15, m=(lane>>4)*4+r.
// ---------------------------------------------------------------------------
__global__ __launch_bounds__(1024)
__attribute__((amdgpu_waves_per_eu(4, 4)))
void schnet_mega(
    const int* __restrict__ z, const float* __restrict__ pos,
    const float* __restrict__ emb, const _Float16* __restrict__ wf,
    const float* __restrict__ mlp_b1, const float* __restrict__ mlp_b2,
    const float* __restrict__ lin2_b, const float* __restrict__ lin_b,
    const float* __restrict__ out_w1, const float* __restrict__ out_b1,
    const float* __restrict__ out_w2, const float* __restrict__ out_b2,
    float* __restrict__ out)
{
  __shared__ __align__(16) _Float16 sWA[28672];     // weight staging (57344 B)
  __shared__ __align__(16) _Float16 sAf[APM*136];   // A-frag f16 buffer (h/agg)
  __shared__ __align__(16) _Float16 sBf[APM*136];   // A-frag f16 buffer (t2)
  __shared__ __align__(16) float    sX1[APM*113];   // x1 fp32 (stride 113)
  __shared__ __align__(16) float    sH [APM*NPAD];  // h state fp32
  __shared__ __align__(16) _Float16 sT[NWAVES][16*40]; // per-wave T chunk (1 mt)
  __shared__ float sD [APM*33];
  __shared__ float sCC[APM*33];
  __shared__ float sB1m[NPAD], sB2m[NPAD], sB2l[NPAD], sBlv[NPAD];
  __shared__ float sPos[APM*3];
  __shared__ float sPart[NWAVES];

  int tid = threadIdx.x, lane = tid & 63, wv = tid >> 6;
  int q = lane >> 4, n = lane & 15;
  int mol = blockIdx.x, mb = mol*APM;

  // ---------------- init ----------------
  if (tid < 96) sPos[tid] = pos[mb*3 + tid];
  if (tid >= 96 && tid < 144){                 // zero bias pads 100..111
    int w = (tid-96)/12, i = 100 + (tid-96)%12;
    (w==0 ? sB1m : w==1 ? sB2m : w==2 ? sB2l : sBlv)[i] = 0.0f;
  }
  if (tid < 512){                              // zero sBf k-pad cols 112..127
    int r0 = tid >> 4, c0 = 112 + (tid & 15);
    sBf[r0*136 + c0] = (_Float16)0.0f;
  }
  for (int i = tid; i < APM*NPAD; i += NTHREADS){ // h init from embedding
    int r = i/NPAD, c = i - r*NPAD;
    sH[i] = (c < FEAT) ? emb[z[mb+r]*FEAT + c] : 0.0f;
  }
  __syncthreads();
  for (int p = tid; p < APM*APM; p += NTHREADS){  // distances + raw cutoff
    int i = p >> 5, j = p & 31;
    float dx = sPos[i*3+0]-sPos[j*3+0];
    float dy = sPos[i*3+1]-sPos[j*3+1];
    float dz = sPos[i*3+2]-sPos[j*3+2];
    float d2 = dx*dx + dy*dy + dz*dz;
    float d = (d2 > 36.0f) ? 6.0f : sqrtf(d2);
    sD[i*33+j]  = d;
    sCC[i*33+j] = 0.5f*(__cosf(d*0.52359877559f) + 1.0f);
  }
  __syncthreads();
  if (tid < APM){                              // drop self + 3 farthest: cc=0
    float dd[32];
    #pragma unroll
    for (int j = 0; j < 32; j++) dd[j] = sD[tid*33+j];
    dd[tid] = 1e30f;
    unsigned dropped = 0u;
    for (int rr = 0; rr < 4; rr++){
      float mx = -1.0f; int mj = 0;
      #pragma unroll
      for (int j = 0; j < 32; j++){
        bool ok = !((dropped>>j)&1u) && (dd[j] > mx);
        mx = ok ? dd[j] : mx;  mj = ok ? j : mj;
      }
      dropped |= 1u << mj;
    }
    #pragma unroll
    for (int j = 0; j < 32; j++)
      if ((dropped>>j)&1u) sCC[tid*33+j] = 0.0f;
  }
  __syncthreads();

  // ---------------- interaction layers ----------------
  for (int l = 0; l < LAYERS; l++){
    const _Float16* wl = wf + l*LWTOT;
    // stage lin1f + biases; cvt sH -> sAf (f16 A-frag rows, k-pad zeros)
    cpw(sWA, wl + L1F_OFF, 14336/8);
    if (tid < 400){
      int w = tid/100, i = tid - w*100;
      float v = (w==0 ? mlp_b1 : w==1 ? mlp_b2 : w==2 ? lin2_b : lin_b)[l*FEAT + i];
      (w==0 ? sB1m : w==1 ? sB2m : w==2 ? sB2l : sBlv)[i] = v;
    }
    for (int i = tid; i < APM*KPAD; i += NTHREADS){
      int r = i >> 7, c = i & 127;
      sAf[r*136+c] = (c < NPAD) ? (_Float16)sH[r*NPAD+c] : (_Float16)0.0f;
    }
    __syncthreads();
    // ---- x1 = h @ lin1 -> sX1 fp32 ----
    for (int tau = wv; tau < 14; tau += NWAVES){
      int mt = tau/7, nt = tau - mt*7;
      f32x4 acc = {0.0f,0.0f,0.0f,0.0f};
      #pragma unroll
      for (int kc = 0; kc < 4; kc++){
        f16x8 a = *(const f16x8*)&sAf[(mt*16+n)*136 + kc*32 + q*8];
        f16x8 b = *(const f16x8*)&sWA[((kc*7+nt)*64 + lane)*8];
        acc = __builtin_amdgcn_mfma_f32_16x16x32_f16(a, b, acc, 0, 0, 0);
      }
      #pragma unroll
      for (int r = 0; r < 4; r++)
        sX1[(mt*16+q*4+r)*113 + nt*16+n] = acc[r];
    }
    __syncthreads();
    cpw(sWA, wl + W1F_OFF, (3584+14336)/8);   // W1f @0, W2f @3584 (contiguous)
    __syncthreads();
    // ---- edge MLP + CFConv agg: wave handles atoms wv*2..wv*2+1;
    //      edges split into two mt passes of 16 to keep live regs < budget
    {
      _Float16* myT = sT[wv];
      #pragma unroll 1
      for (int t = 0; t < 2; t++){
        int a = wv*2 + t;
        float aggv[7];
        #pragma unroll
        for (int nt = 0; nt < 7; nt++) aggv[nt] = 0.0f;
        #pragma unroll 1
        for (int mt = 0; mt < 2; mt++){
          f16x8 eaA;                           // gaussian A-frag, this mt
          {
            float d = sD[a*33 + mt*16 + n];
            #pragma unroll
            for (int j = 0; j < 8; j++){
              int g = q*8 + j;
              float dd2 = d - 0.25f*(float)g;
              float v = (g < 25) ? __expf(-8.0f*dd2*dd2) : 0.0f;
              eaA[j] = (_Float16)v;
            }
          }
          f32x4 acc2[7];
          #pragma unroll
          for (int nt = 0; nt < 7; nt++)
            acc2[nt] = (f32x4){0.0f,0.0f,0.0f,0.0f};
          #pragma unroll 1
          for (int kc = 0; kc < 4; kc++){
            #pragma unroll
            for (int hh = 0; hh < 2; hh++){
              int nt1 = kc*2 + hh;
              if (nt1 < 7){
                f16x8 bf = *(const f16x8*)&sWA[(nt1*64 + lane)*8];
                float bb = sB1m[nt1*16 + n];
                f32x4 c = __builtin_amdgcn_mfma_f32_16x16x32_f16(eaA, bf,
                            (f32x4){0.0f,0.0f,0.0f,0.0f}, 0, 0, 0);
                #pragma unroll
                for (int r = 0; r < 4; r++)
                  myT[(q*4+r)*40 + hh*16 + n] = (_Float16)sspf(c[r] + bb);
              } else {  // kc==3,hh==1: zero T pad cols 16..31 (feat 112..127)
                if (lane < 32)
                  *(f16x8*)&myT[(lane & 15)*40 + 16 + (lane >> 4)*8] =
                      (f16x8){0,0,0,0,0,0,0,0};
              }
            }
            f16x8 aT = *(const f16x8*)&myT[n*40 + q*8];
            #pragma unroll
            for (int nt = 0; nt < 7; nt++){
              f16x8 bf = *(const f16x8*)&sWA[3584 + ((kc*7+nt)*64 + lane)*8];
              acc2[nt] = __builtin_amdgcn_mfma_f32_16x16x32_f16(
                           aT, bf, acc2[nt], 0, 0, 0);
            }
          }
          // epilogue for this mt: Wf=acc+b2, msg = cc*Wf*x1[e], accumulate
          #pragma unroll
          for (int r = 0; r < 4; r++){
            int e = mt*16 + q*4 + r;
            float cc = sCC[a*33 + e];
            #pragma unroll
            for (int nt = 0; nt < 7; nt++){
              float wfv = acc2[nt][r] + sB2m[nt*16+n];
              aggv[nt] += (cc*wfv) * sX1[e*113 + nt*16+n];
            }
          }
        }
        #pragma unroll
        for (int nt = 0; nt < 7; nt++){
          aggv[nt] += __shfl_xor(aggv[nt], 16);
          aggv[nt] += __shfl_xor(aggv[nt], 32);
        }
        if (lane < 16){
          #pragma unroll
          for (int nt = 0; nt < 7; nt++)
            sAf[a*136 + nt*16 + lane] = (_Float16)aggv[nt];
          sAf[a*136 + 112 + lane] = (_Float16)0.0f;   // k-pad for next GEMM
        }
      }
    }
    __syncthreads();
    // stage lin2f + linf together (contiguous in prepped buffer)
    cpw(sWA, wl + L2F_OFF, (14336+14336)/8);
    __syncthreads();
    // ---- t2 = ssp(agg @ lin2 + b2l) -> sBf f16 ----
    for (int tau = wv; tau < 14; tau += NWAVES){
      int mt = tau/7, nt = tau - mt*7;
      f32x4 acc = {0.0f,0.0f,0.0f,0.0f};
      #pragma unroll
      for (int kc = 0; kc < 4; kc++){
        f16x8 a = *(const f16x8*)&sAf[(mt*16+n)*136 + kc*32 + q*8];
        f16x8 b = *(const f16x8*)&sWA[((kc*7+nt)*64 + lane)*8];
        acc = __builtin_amdgcn_mfma_f32_16x16x32_f16(a, b, acc, 0, 0, 0);
      }
      float bb = sB2l[nt*16+n];
      #pragma unroll
      for (int r = 0; r < 4; r++)
        sBf[(mt*16+q*4+r)*136 + nt*16+n] = (_Float16)sspf(acc[r] + bb);
    }
    __syncthreads();
    // ---- v = t2 @ lin + bl ; h += v  (linf staged at sWA+14336) ----
    for (int tau = wv; tau < 14; tau += NWAVES){
      int mt = tau/7, nt = tau - mt*7;
      f32x4 acc = {0.0f,0.0f,0.0f,0.0f};
      #pragma unroll
      for (int kc = 0; kc < 4; kc++){
        f16x8 a = *(const f16x8*)&sBf[(mt*16+n)*136 + kc*32 + q*8];
        f16x8 b = *(const f16x8*)&sWA[14336 + ((kc*7+nt)*64 + lane)*8];
        acc = __builtin_amdgcn_mfma_f32_16x16x32_f16(a, b, acc, 0, 0, 0);
      }
      int f = nt*16 + n;
      if (f < FEAT){
        float bb = sBlv[f];
        #pragma unroll
        for (int r = 0; r < 4; r++)
          sH[(mt*16+q*4+r)*NPAD + f] += acc[r] + bb;
      }
    }
    __syncthreads();
  }

  // ---------------- readout ----------------
  float* rw = (float*)sWA;                     // out_w1 [100][50] fp32
  for (int i = tid; i < 5000; i += NTHREADS) rw[i] = out_w1[i];
  if (tid < 50){ sB1m[tid] = out_b1[tid]; sB2m[tid] = out_w2[tid]; }
  __syncthreads();
  float ob2 = out_b2[0];
  float partial = 0.0f;
  for (int t = 0; t < 2; t++){
    int a = wv*2 + t;
    float u = 0.0f;
    if (lane < 50){
      u = sB1m[lane];
      #pragma unroll 4
      for (int c = 0; c < FEAT; c++)
        u += sH[a*NPAD + c] * rw[c*50 + lane];
      u = sspf(u) * sB2m[lane];
    }
    #pragma unroll
    for (int s = 1; s < 64; s <<= 1) u += __shfl_xor(u, s);
    partial += u + ob2;
  }
  if (lane == 0) sPart[wv] = partial;
  __syncthreads();
  if (tid == 0){
    float s = 0.0f;
    #pragma unroll
    for (int i = 0; i < NWAVES; i++) s += sPart[i];
    out[mol] = s;
  }
}

extern "C" void kernel_launch(void* const* d_in, const int* in_sizes, int n_in,
                              void* d_out, int out_size, void* d_ws, size_t ws_size,
                              hipStream_t stream)
{
  const int*   z      = (const int*)  d_in[0];
  const float* pos    = (const float*)d_in[1];
  /* d_in[2] = ptr: molecules are fixed 32-atom blocks; unused */
  const float* emb    = (const float*)d_in[3];
  const float* mlp_w1 = (const float*)d_in[4];
  const float* mlp_b1 = (const float*)d_in[5];
  const float* mlp_w2 = (const float*)d_in[6];
  const float* mlp_b2 = (const float*)d_in[7];
  const float* lin1_w = (const float*)d_in[8];
  const float* lin2_w = (const float*)d_in[9];
  const float* lin2_b = (const float*)d_in[10];
  const float* lin_w  = (const float*)d_in[11];
  const float* lin_b  = (const float*)d_in[12];
  const float* out_w1 = (const float*)d_in[13];
  const float* out_b1 = (const float*)d_in[14];
  const float* out_w2 = (const float*)d_in[15];
  const float* out_b2 = (const float*)d_in[16];

  _Float16* wfrag = (_Float16*)d_ws;           // 243712 f16 = 487 KB

  prep_weights<<<WTOTAL/256, 256, 0, stream>>>(mlp_w1, mlp_w2, lin1_w,
                                               lin2_w, lin_w, wfrag);
  schnet_mega<<<NMOL, NTHREADS, 0, stream>>>(z, pos, emb, wfrag,
      mlp_b1, mlp_b2, lin2_b, lin_b,
      out_w1, out_b1, out_w2, out_b2, (float*)d_out);
}

// Round 5
// 219.837 us; speedup vs baseline: 1.2106x; 1.0071x over previous
//
#include <hip/hip_runtime.h>
#include <math.h>

#define APM   32
#define NMOL  256
#define FEAT  100
#define NPAD  112
#define KPAD  128
#define LAYERS 4
#define NTHREADS 1024
#define NWAVES   16

typedef _Float16 f16x8 __attribute__((ext_vector_type(8)));
typedef float    f32x4 __attribute__((ext_vector_type(4)));

// per-layer f16 frag-weight block layout in ws (element offsets)
#define L1F_OFF 0        // lin1f  14336
#define W1F_OFF 14336    // W1f    3584
#define W2F_OFF 17920    // W2f    14336
#define L2F_OFF 32256    // lin2f  14336
#define LVF_OFF 46592    // linf   14336
#define LWTOT 60928      // per layer
#define WTOTAL  (4*LWTOT) // 243712

__device__ __forceinline__ float sspf(float x){
  // ssp(x) = log(1+e^x) - log2. R5: direct form (5-6 VALU vs 9 for the
  // fmax+exp(-|x|) branchless form). e^x overflows only at x>88 — inputs
  // here are small-MLP preactivations feeding f16, |x| << 88. x->-inf
  // limit is exact (-log2). The trailing sub fuses into __logf's fma.
  return __logf(1.0f + __expf(x)) - 0.69314718056f;
}

// ---------------------------------------------------------------------------
// One-time weight conversion into f16 MFMA B-fragment order:
//   Bf[((kc*7+nt)*64 + lane)*8 + j] = W[k][f],  k = kc*32+(lane>>4)*8+j,
//   f = nt*16+(lane&15); zero outside (Kdim, 100). Validated layout (R3).
// ---------------------------------------------------------------------------
__global__ __launch_bounds__(256) void prep_weights(
    const float* __restrict__ mlp_w1, const float* __restrict__ mlp_w2,
    const float* __restrict__ lin1_w, const float* __restrict__ lin2_w,
    const float* __restrict__ lin_w,  _Float16* __restrict__ out)
{
  int gid = blockIdx.x*256 + threadIdx.x;      // < 243712 exactly
  int l = gid / LWTOT;
  int r = gid - l*LWTOT;
  const float* W; int Kdim; int e;
  if (r < 14336)      { W = lin1_w + l*10000; Kdim = 100; e = r; }
  else if (r < 17920) { W = mlp_w1 + l*2500;  Kdim = 25;  e = r - 14336; }
  else if (r < 32256) { W = mlp_w2 + l*10000; Kdim = 100; e = r - 17920; }
  else if (r < 46592) { W = lin2_w + l*10000; Kdim = 100; e = r - 32256; }
  else                { W = lin_w  + l*10000; Kdim = 100; e = r - 46592; }
  int j = e & 7, L = (e >> 3) & 63, tile = e >> 9;
  int kc = tile / 7, nt = tile - kc*7;
  int k = kc*32 + ((L >> 4) << 3) + j;
  int f = nt*16 + (L & 15);
  float v = (k < Kdim && f < FEAT) ? W[k*FEAT + f] : 0.0f;
  out[gid] = (_Float16)v;
}

__device__ __forceinline__ void cpw(_Float16* dst, const _Float16* src, int n16){
  const uint4* s = (const uint4*)src;
  uint4* d = (uint4*)dst;
  for (int i = threadIdx.x; i < n16; i += NTHREADS) d[i] = s[i];
}

// ---------------------------------------------------------------------------
// Whole network per molecule in one block: graph + emb + 4 interaction layers
// + readout. 1024 threads = 16 waves, 1 block/CU (LDS-capped) = 4 waves/EU.
// R4 killed the scratch spills (WRITE_SIZE 180MB->8KB, 194->155us); now
// VALU-issue-bound (VALUBusy 70%, MfmaUtil 11%, HBM 0.2%). R5 VALU diet:
// (1) sspf direct form; (2) x1 stored transposed sX1t[f][e] stride 36 ->
// f32x4 write in x1-GEMM epilogue (1 b128 vs 4 b32) and f32x4 reads in the
// CFConv epilogue (7 b128 vs 28 b32 per pass); (3) cc/b2 hoisted to regs.
// MFMA layouts (validated in R3): A: m=lane&15,k=(lane>>4)*8+j ; C/D:
// n=lane&15, m=(lane>>4)*4+r.
// ---------------------------------------------------------------------------
__global__ __launch_bounds__(1024)
__attribute__((amdgpu_waves_per_eu(4, 4)))
void schnet_mega(
    const int* __restrict__ z, const float* __restrict__ pos,
    const float* __restrict__ emb, const _Float16* __restrict__ wf,
    const float* __restrict__ mlp_b1, const float* __restrict__ mlp_b2,
    const float* __restrict__ lin2_b, const float* __restrict__ lin_b,
    const float* __restrict__ out_w1, const float* __restrict__ out_b1,
    const float* __restrict__ out_w2, const float* __restrict__ out_b2,
    float* __restrict__ out)
{
  __shared__ __align__(16) _Float16 sWA[28672];     // weight staging (57344 B)
  __shared__ __align__(16) _Float16 sAf[APM*136];   // A-frag f16 buffer (h/agg)
  __shared__ __align__(16) _Float16 sBf[APM*136];   // A-frag f16 buffer (t2)
  __shared__ __align__(16) float    sX1t[NPAD*36];  // x1 fp32 TRANSPOSED [f][e]
  __shared__ __align__(16) float    sH [APM*NPAD];  // h state fp32
  __shared__ __align__(16) _Float16 sT[NWAVES][16*40]; // per-wave T chunk (1 mt)
  __shared__ float sD [APM*33];
  __shared__ float sCC[APM*33];
  __shared__ float sB1m[NPAD], sB2m[NPAD], sB2l[NPAD], sBlv[NPAD];
  __shared__ float sPos[APM*3];
  __shared__ float sPart[NWAVES];

  int tid = threadIdx.x, lane = tid & 63, wv = tid >> 6;
  int q = lane >> 4, n = lane & 15;
  int mol = blockIdx.x, mb = mol*APM;

  // ---------------- init ----------------
  if (tid < 96) sPos[tid] = pos[mb*3 + tid];
  if (tid >= 96 && tid < 144){                 // zero bias pads 100..111
    int w = (tid-96)/12, i = 100 + (tid-96)%12;
    (w==0 ? sB1m : w==1 ? sB2m : w==2 ? sB2l : sBlv)[i] = 0.0f;
  }
  if (tid < 512){                              // zero sBf k-pad cols 112..127
    int r0 = tid >> 4, c0 = 112 + (tid & 15);
    sBf[r0*136 + c0] = (_Float16)0.0f;
  }
  for (int i = tid; i < APM*NPAD; i += NTHREADS){ // h init from embedding
    int r = i/NPAD, c = i - r*NPAD;
    sH[i] = (c < FEAT) ? emb[z[mb+r]*FEAT + c] : 0.0f;
  }
  __syncthreads();
  for (int p = tid; p < APM*APM; p += NTHREADS){  // distances + raw cutoff
    int i = p >> 5, j = p & 31;
    float dx = sPos[i*3+0]-sPos[j*3+0];
    float dy = sPos[i*3+1]-sPos[j*3+1];
    float dz = sPos[i*3+2]-sPos[j*3+2];
    float d2 = dx*dx + dy*dy + dz*dz;
    float d = (d2 > 36.0f) ? 6.0f : sqrtf(d2);
    sD[i*33+j]  = d;
    sCC[i*33+j] = 0.5f*(__cosf(d*0.52359877559f) + 1.0f);
  }
  __syncthreads();
  if (tid < APM){                              // drop self + 3 farthest: cc=0
    float dd[32];
    #pragma unroll
    for (int j = 0; j < 32; j++) dd[j] = sD[tid*33+j];
    dd[tid] = 1e30f;
    unsigned dropped = 0u;
    for (int rr = 0; rr < 4; rr++){
      float mx = -1.0f; int mj = 0;
      #pragma unroll
      for (int j = 0; j < 32; j++){
        bool ok = !((dropped>>j)&1u) && (dd[j] > mx);
        mx = ok ? dd[j] : mx;  mj = ok ? j : mj;
      }
      dropped |= 1u << mj;
    }
    #pragma unroll
    for (int j = 0; j < 32; j++)
      if ((dropped>>j)&1u) sCC[tid*33+j] = 0.0f;
  }
  __syncthreads();

  // ---------------- interaction layers ----------------
  for (int l = 0; l < LAYERS; l++){
    const _Float16* wl = wf + l*LWTOT;
    // stage lin1f + biases; cvt sH -> sAf (f16 A-frag rows, k-pad zeros)
    cpw(sWA, wl + L1F_OFF, 14336/8);
    if (tid < 400){
      int w = tid/100, i = tid - w*100;
      float v = (w==0 ? mlp_b1 : w==1 ? mlp_b2 : w==2 ? lin2_b : lin_b)[l*FEAT + i];
      (w==0 ? sB1m : w==1 ? sB2m : w==2 ? sB2l : sBlv)[i] = v;
    }
    for (int i = tid; i < APM*KPAD; i += NTHREADS){
      int r = i >> 7, c = i & 127;
      sAf[r*136+c] = (c < NPAD) ? (_Float16)sH[r*NPAD+c] : (_Float16)0.0f;
    }
    __syncthreads();
    // ---- x1 = h @ lin1 -> sX1t fp32 transposed [f][e], vector store ----
    for (int tau = wv; tau < 14; tau += NWAVES){
      int mt = tau/7, nt = tau - mt*7;
      f32x4 acc = {0.0f,0.0f,0.0f,0.0f};
      #pragma unroll
      for (int kc = 0; kc < 4; kc++){
        f16x8 a = *(const f16x8*)&sAf[(mt*16+n)*136 + kc*32 + q*8];
        f16x8 b = *(const f16x8*)&sWA[((kc*7+nt)*64 + lane)*8];
        acc = __builtin_amdgcn_mfma_f32_16x16x32_f16(a, b, acc, 0, 0, 0);
      }
      // acc[r] = x1[e = mt*16+q*4+r][f = nt*16+n]; e contiguous -> b128
      *(f32x4*)&sX1t[(nt*16+n)*36 + mt*16 + q*4] = acc;
    }
    __syncthreads();
    cpw(sWA, wl + W1F_OFF, (3584+14336)/8);   // W1f @0, W2f @3584 (contiguous)
    __syncthreads();
    // ---- edge MLP + CFConv agg: wave handles atoms wv*2..wv*2+1;
    //      edges split into two mt passes of 16 to keep live regs < budget
    {
      _Float16* myT = sT[wv];
      #pragma unroll 1
      for (int t = 0; t < 2; t++){
        int a = wv*2 + t;
        float aggv[7];
        #pragma unroll
        for (int nt = 0; nt < 7; nt++) aggv[nt] = 0.0f;
        #pragma unroll 1
        for (int mt = 0; mt < 2; mt++){
          f16x8 eaA;                           // gaussian A-frag, this mt
          {
            float d = sD[a*33 + mt*16 + n];
            #pragma unroll
            for (int j = 0; j < 8; j++){
              int g = q*8 + j;
              float dd2 = d - 0.25f*(float)g;
              float v = (g < 25) ? __expf(-8.0f*dd2*dd2) : 0.0f;
              eaA[j] = (_Float16)v;
            }
          }
          f32x4 acc2[7];
          #pragma unroll
          for (int nt = 0; nt < 7; nt++)
            acc2[nt] = (f32x4){0.0f,0.0f,0.0f,0.0f};
          #pragma unroll 1
          for (int kc = 0; kc < 4; kc++){
            #pragma unroll
            for (int hh = 0; hh < 2; hh++){
              int nt1 = kc*2 + hh;
              if (nt1 < 7){
                f16x8 bf = *(const f16x8*)&sWA[(nt1*64 + lane)*8];
                float bb = sB1m[nt1*16 + n];
                f32x4 c = __builtin_amdgcn_mfma_f32_16x16x32_f16(eaA, bf,
                            (f32x4){0.0f,0.0f,0.0f,0.0f}, 0, 0, 0);
                #pragma unroll
                for (int r = 0; r < 4; r++)
                  myT[(q*4+r)*40 + hh*16 + n] = (_Float16)sspf(c[r] + bb);
              } else {  // kc==3,hh==1: zero T pad cols 16..31 (feat 112..127)
                if (lane < 32)
                  *(f16x8*)&myT[(lane & 15)*40 + 16 + (lane >> 4)*8] =
                      (f16x8){0,0,0,0,0,0,0,0};
              }
            }
            f16x8 aT = *(const f16x8*)&myT[n*40 + q*8];
            #pragma unroll
            for (int nt = 0; nt < 7; nt++){
              f16x8 bf = *(const f16x8*)&sWA[3584 + ((kc*7+nt)*64 + lane)*8];
              acc2[nt] = __builtin_amdgcn_mfma_f32_16x16x32_f16(
                           aT, bf, acc2[nt], 0, 0, 0);
            }
          }
          // epilogue for this mt: Wf=acc+b2, msg = cc*Wf*x1[e], accumulate
          float ccv[4];
          #pragma unroll
          for (int r = 0; r < 4; r++)
            ccv[r] = sCC[a*33 + mt*16 + q*4 + r];
          #pragma unroll
          for (int nt = 0; nt < 7; nt++){
            f32x4 x4 = *(const f32x4*)&sX1t[(nt*16+n)*36 + mt*16 + q*4];
            float b2v = sB2m[nt*16+n];
            #pragma unroll
            for (int r = 0; r < 4; r++){
              float wfv = acc2[nt][r] + b2v;
              aggv[nt] += (ccv[r]*wfv) * x4[r];
            }
          }
        }
        #pragma unroll
        for (int nt = 0; nt < 7; nt++){
          aggv[nt] += __shfl_xor(aggv[nt], 16);
          aggv[nt] += __shfl_xor(aggv[nt], 32);
        }
        if (lane < 16){
          #pragma unroll
          for (int nt = 0; nt < 7; nt++)
            sAf[a*136 + nt*16 + lane] = (_Float16)aggv[nt];
          sAf[a*136 + 112 + lane] = (_Float16)0.0f;   // k-pad for next GEMM
        }
      }
    }
    __syncthreads();
    // stage lin2f + linf together (contiguous in prepped buffer)
    cpw(sWA, wl + L2F_OFF, (14336+14336)/8);
    __syncthreads();
    // ---- t2 = ssp(agg @ lin2 + b2l) -> sBf f16 ----
    for (int tau = wv; tau < 14; tau += NWAVES){
      int mt = tau/7, nt = tau - mt*7;
      f32x4 acc = {0.0f,0.0f,0.0f,0.0f};
      #pragma unroll
      for (int kc = 0; kc < 4; kc++){
        f16x8 a = *(const f16x8*)&sAf[(mt*16+n)*136 + kc*32 + q*8];
        f16x8 b = *(const f16x8*)&sWA[((kc*7+nt)*64 + lane)*8];
        acc = __builtin_amdgcn_mfma_f32_16x16x32_f16(a, b, acc, 0, 0, 0);
      }
      float bb = sB2l[nt*16+n];
      #pragma unroll
      for (int r = 0; r < 4; r++)
        sBf[(mt*16+q*4+r)*136 + nt*16+n] = (_Float16)sspf(acc[r] + bb);
    }
    __syncthreads();
    // ---- v = t2 @ lin + bl ; h += v  (linf staged at sWA+14336) ----
    for (int tau = wv; tau < 14; tau += NWAVES){
      int mt = tau/7, nt = tau - mt*7;
      f32x4 acc = {0.0f,0.0f,0.0f,0.0f};
      #pragma unroll
      for (int kc = 0; kc < 4; kc++){
        f16x8 a = *(const f16x8*)&sBf[(mt*16+n)*136 + kc*32 + q*8];
        f16x8 b = *(const f16x8*)&sWA[14336 + ((kc*7+nt)*64 + lane)*8];
        acc = __builtin_amdgcn_mfma_f32_16x16x32_f16(a, b, acc, 0, 0, 0);
      }
      int f = nt*16 + n;
      if (f < FEAT){
        float bb = sBlv[f];
        #pragma unroll
        for (int r = 0; r < 4; r++)
          sH[(mt*16+q*4+r)*NPAD + f] += acc[r] + bb;
      }
    }
    __syncthreads();
  }

  // ---------------- readout ----------------
  float* rw = (float*)sWA;                     // out_w1 [100][50] fp32
  for (int i = tid; i < 5000; i += NTHREADS) rw[i] = out_w1[i];
  if (tid < 50){ sB1m[tid] = out_b1[tid]; sB2m[tid] = out_w2[tid]; }
  __syncthreads();
  float ob2 = out_b2[0];
  float partial = 0.0f;
  for (int t = 0; t < 2; t++){
    int a = wv*2 + t;
    float u = 0.0f;
    if (lane < 50){
      u = sB1m[lane];
      #pragma unroll 4
      for (int c = 0; c < FEAT; c++)
        u += sH[a*NPAD + c] * rw[c*50 + lane];
      u = sspf(u) * sB2m[lane];
    }
    #pragma unroll
    for (int s = 1; s < 64; s <<= 1) u += __shfl_xor(u, s);
    partial += u + ob2;
  }
  if (lane == 0) sPart[wv] = partial;
  __syncthreads();
  if (tid == 0){
    float s = 0.0f;
    #pragma unroll
    for (int i = 0; i < NWAVES; i++) s += sPart[i];
    out[mol] = s;
  }
}

extern "C" void kernel_launch(void* const* d_in, const int* in_sizes, int n_in,
                              void* d_out, int out_size, void* d_ws, size_t ws_size,
                              hipStream_t stream)
{
  const int*   z      = (const int*)  d_in[0];
  const float* pos    = (const float*)d_in[1];
  /* d_in[2] = ptr: molecules are fixed 32-atom blocks; unused */
  const float* emb    = (const float*)d_in[3];
  const float* mlp_w1 = (const float*)d_in[4];
  const float* mlp_b1 = (const float*)d_in[5];
  const float* mlp_w2 = (const float*)d_in[6];
  const float* mlp_b2 = (const float*)d_in[7];
  const float* lin1_w = (const float*)d_in[8];
  const float* lin2_w = (const float*)d_in[9];
  const float* lin2_b = (const float*)d_in[10];
  const float* lin_w  = (const float*)d_in[11];
  const float* lin_b  = (const float*)d_in[12];
  const float* out_w1 = (const float*)d_in[13];
  const float* out_b1 = (const float*)d_in[14];
  const float* out_w2 = (const float*)d_in[15];
  const float* out_b2 = (const float*)d_in[16];

  _Float16* wfrag = (_Float16*)d_ws;           // 243712 f16 = 487 KB

  prep_weights<<<WTOTAL/256, 256, 0, stream>>>(mlp_w1, mlp_w2, lin1_w,
                                               lin2_w, lin_w, wfrag);
  schnet_mega<<<NMOL, NTHREADS, 0, stream>>>(z, pos, emb, wfrag,
      mlp_b1, mlp_b2, lin2_b, lin_b,
      out_w1, out_b1, out_w2, out_b2, (float*)d_out);
}

// Round 6
// 166.109 us; speedup vs baseline: 1.6022x; 1.3235x over previous
//
#include <hip/hip_runtime.h>
#include <math.h>

#define APM   32
#define NMOL  256
#define FEAT  100
#define NPAD  112
#define LAYERS 4
#define NTHREADS 1024
#define NWAVES   16
#define G_TBL 1024
#define TSTR  128            // table row stride (f32 elems)
#define X1STR 132            // sX1 row stride (f32 elems)

typedef _Float16 f16x8 __attribute__((ext_vector_type(8)));
typedef float    f32x4 __attribute__((ext_vector_type(4)));

// per-layer f16 frag-weight block layout in ws (element offsets)
// R6: edge-MLP weights (W1/W2) no longer fragged — the whole edge filter is
// tabulated over d. Only lin1/lin2/lin remain.
#define L1F_OFF 0        // lin1f  14336
#define L2F_OFF 14336    // lin2f  14336
#define LVF_OFF 28672    // linf   14336
#define LWTOT   43008    // per layer
#define WTOTAL  (4*LWTOT) // 172032 f16 = 344064 B

__device__ __forceinline__ float sspf(float x){
  // ssp(x) = log(1+e^x) - log2 (direct form, R5)
  return __logf(1.0f + __expf(x)) - 0.69314718056f;
}

// ---------------------------------------------------------------------------
// One-time weight conversion into f16 MFMA B-fragment order:
//   Bf[((kc*7+nt)*64 + lane)*8 + j] = W[k][f],  k = kc*32+(lane>>4)*8+j,
//   f = nt*16+(lane&15); zero outside (100,100). Validated layout (R3).
// ---------------------------------------------------------------------------
__global__ __launch_bounds__(256) void prep_weights(
    const float* __restrict__ lin1_w, const float* __restrict__ lin2_w,
    const float* __restrict__ lin_w,  _Float16* __restrict__ out)
{
  int gid = blockIdx.x*256 + threadIdx.x;      // < 172032 exactly
  int l = gid / LWTOT;
  int r = gid - l*LWTOT;
  const float* W; int e;
  if (r < 14336)      { W = lin1_w + l*10000; e = r; }
  else if (r < 28672) { W = lin2_w + l*10000; e = r - 14336; }
  else                { W = lin_w  + l*10000; e = r - 28672; }
  int j = e & 7, L = (e >> 3) & 63, tile = e >> 9;
  int kc = tile / 7, nt = tile - kc*7;
  int k = kc*32 + ((L >> 4) << 3) + j;
  int f = nt*16 + (L & 15);
  float v = (k < 100 && f < FEAT) ? W[k*FEAT + f] : 0.0f;
  out[gid] = (_Float16)v;
}

// ---------------------------------------------------------------------------
// R6: build the per-layer edge-filter table over the distance grid:
//   tbl[l][s][f] = cc(d_s) * ( ssp(ea(d_s)@W1 + b1) @ W2 + b2 )[f]
// d_s = 6*s/(G-1). The entire edge MLP is a function of the scalar d only.
// 1024 blocks x 256 thr; each wave builds one (l,s) entry. f in [100,128)
// stored as 0 so gather lanes 36..63 (f1 in [100,127]) read exact zeros.
// ---------------------------------------------------------------------------
__global__ __launch_bounds__(256) void build_table(
    const float* __restrict__ mlp_w1, const float* __restrict__ mlp_b1,
    const float* __restrict__ mlp_w2, const float* __restrict__ mlp_b2,
    float* __restrict__ tbl)
{
  __shared__ float sT[4][100];
  int wv = threadIdx.x >> 6, lane = threadIdx.x & 63;
  int l = blockIdx.x >> 8;                 // 256 blocks per layer
  int s = (blockIdx.x & 255)*4 + wv;       // one grid point per wave
  float d = 6.0f * (float)s / (float)(G_TBL - 1);
  float ea[25];
  #pragma unroll
  for (int g = 0; g < 25; g++){
    float u = d - 0.25f*(float)g;
    ea[g] = __expf(-8.0f*u*u);
  }
  #pragma unroll
  for (int kk = 0; kk < 2; kk++){
    int k = lane + kk*64;
    if (k < 100){
      float acc = mlp_b1[l*100 + k];
      #pragma unroll
      for (int g = 0; g < 25; g++)
        acc += ea[g] * mlp_w1[(l*25 + g)*100 + k];
      sT[wv][k] = sspf(acc);
    }
  }
  // wave-local LDS RAW: compiler-inserted lgkmcnt orders write->read
  float cc = 0.5f*(__cosf(d*0.52359877559f) + 1.0f);
  #pragma unroll
  for (int ff = 0; ff < 2; ff++){
    int f = lane + ff*64;
    float o = 0.0f;
    if (f < 100){
      o = mlp_b2[l*100 + f];
      for (int k = 0; k < 100; k++)
        o += sT[wv][k] * mlp_w2[(l*100 + k)*100 + f];
      o *= cc;
    }
    tbl[((size_t)l*G_TBL + s)*TSTR + f] = o;   // f in [100,128) -> 0
  }
}

__device__ __forceinline__ void cpw(_Float16* dst, const _Float16* src, int n16){
  const uint4* s = (const uint4*)src;
  uint4* d = (uint4*)dst;
  for (int i = threadIdx.x; i < n16; i += NTHREADS) d[i] = s[i];
}

// ---------------------------------------------------------------------------
// Whole network per molecule in one block. 1024 thr = 16 waves, 1 block/CU.
// R4 killed scratch spills; R5 trimmed addressing; R6 replaces the entire
// edge MLP (85% of FLOPs, all sspf/exp trans-ops, T round-trip, W1f/W2f
// staging) with a d-indexed lerp table gather:
//   agg[i][f] = sum_j mask_ij * lerp(tbl_l, d_ij)[f] * x1[j][f]
// lane-per-feature (f0=lane, f1=lane+64), wave-uniform table row per edge
// -> coalesced L2 reads; lin2+linf staging overlaps the gather.
// MFMA layouts (validated R3): A: m=lane&15,k=(lane>>4)*8+j ; C/D:
// n=lane&15, m=(lane>>4)*4+r.
// ---------------------------------------------------------------------------
__global__ __launch_bounds__(1024)
__attribute__((amdgpu_waves_per_eu(4, 4)))
void schnet_mega(
    const int* __restrict__ z, const float* __restrict__ pos,
    const float* __restrict__ emb, const _Float16* __restrict__ wf,
    const float* __restrict__ tbl,
    const float* __restrict__ lin2_b, const float* __restrict__ lin_b,
    const float* __restrict__ out_w1, const float* __restrict__ out_b1,
    const float* __restrict__ out_w2, const float* __restrict__ out_b2,
    float* __restrict__ out)
{
  __shared__ __align__(16) _Float16 sWA[28672];     // weight staging (57344 B)
  __shared__ __align__(16) _Float16 sAf[APM*136];   // A-frag f16 (h / agg)
  __shared__ __align__(16) _Float16 sBf[APM*136];   // A-frag f16 (t2)
  __shared__ __align__(16) float    sX1[APM*X1STR]; // x1 fp32 row-major
  __shared__ __align__(16) float    sH [APM*NPAD];  // h state fp32
  __shared__ float sD [APM*33];
  __shared__ float sM [APM*33];                     // 0/1 edge mask
  __shared__ float sB2l[NPAD], sBlv[NPAD];
  __shared__ float sPos[APM*3];
  __shared__ float sPart[NWAVES];

  int tid = threadIdx.x, lane = tid & 63, wv = tid >> 6;
  int q = lane >> 4, n = lane & 15;
  int mol = blockIdx.x, mb = mol*APM;

  // ---------------- init ----------------
  if (tid < 96) sPos[tid] = pos[mb*3 + tid];
  if (tid < 512){                              // zero sBf k-pad cols 112..127
    int r0 = tid >> 4, c0 = 112 + (tid & 15);
    sBf[r0*136 + c0] = (_Float16)0.0f;
  }
  for (int i = tid; i < APM*NPAD; i += NTHREADS){ // h init from embedding
    int r = i/NPAD, c = i - r*NPAD;
    sH[i] = (c < FEAT) ? emb[z[mb+r]*FEAT + c] : 0.0f;
  }
  __syncthreads();
  for (int p = tid; p < APM*APM; p += NTHREADS){  // distances + mask init
    int i = p >> 5, j = p & 31;
    float dx = sPos[i*3+0]-sPos[j*3+0];
    float dy = sPos[i*3+1]-sPos[j*3+1];
    float dz = sPos[i*3+2]-sPos[j*3+2];
    float d2 = dx*dx + dy*dy + dz*dz;
    float d = (d2 > 36.0f) ? 6.0f : sqrtf(d2);
    sD[i*33+j] = d;
    sM[i*33+j] = 1.0f;
  }
  __syncthreads();
  if (tid < APM){                              // drop self + 3 farthest
    float dd[32];
    #pragma unroll
    for (int j = 0; j < 32; j++) dd[j] = sD[tid*33+j];
    dd[tid] = 1e30f;
    unsigned dropped = 0u;
    for (int rr = 0; rr < 4; rr++){
      float mx = -1.0f; int mj = 0;
      #pragma unroll
      for (int j = 0; j < 32; j++){
        bool ok = !((dropped>>j)&1u) && (dd[j] > mx);
        mx = ok ? dd[j] : mx;  mj = ok ? j : mj;
      }
      dropped |= 1u << mj;
    }
    #pragma unroll
    for (int j = 0; j < 32; j++)
      if ((dropped>>j)&1u) sM[tid*33+j] = 0.0f;
  }
  __syncthreads();

  // ---------------- interaction layers ----------------
  for (int l = 0; l < LAYERS; l++){
    const _Float16* wl = wf + l*LWTOT;
    const float* tb = tbl + (size_t)l*G_TBL*TSTR;
    // stage lin1f + biases; cvt sH -> sAf (f16 A-frag rows, k-pad zeros)
    cpw(sWA, wl + L1F_OFF, 14336/8);
    if (tid < 224){
      int w = tid/112, i = tid - w*112;
      float v = (i < FEAT) ? (w==0 ? lin2_b : lin_b)[l*FEAT + i] : 0.0f;
      (w==0 ? sB2l : sBlv)[i] = v;
    }
    for (int i = tid; i < APM*128; i += NTHREADS){
      int r = i >> 7, c = i & 127;
      sAf[r*136+c] = (c < NPAD) ? (_Float16)sH[r*NPAD+c] : (_Float16)0.0f;
    }
    __syncthreads();
    // ---- x1 = h @ lin1 -> sX1 row-major fp32 ----
    for (int tau = wv; tau < 14; tau += NWAVES){
      int mt = tau/7, nt = tau - mt*7;
      f32x4 acc = {0.0f,0.0f,0.0f,0.0f};
      #pragma unroll
      for (int kc = 0; kc < 4; kc++){
        f16x8 a = *(const f16x8*)&sAf[(mt*16+n)*136 + kc*32 + q*8];
        f16x8 b = *(const f16x8*)&sWA[((kc*7+nt)*64 + lane)*8];
        acc = __builtin_amdgcn_mfma_f32_16x16x32_f16(a, b, acc, 0, 0, 0);
      }
      #pragma unroll
      for (int r = 0; r < 4; r++)
        sX1[(mt*16+q*4+r)*X1STR + nt*16+n] = acc[r];
    }
    __syncthreads();
    // stage lin2f+linf (contiguous) — overlaps the gather (disjoint LDS)
    cpw(sWA, wl + L2F_OFF, 28672/8);
    // ---- CFConv gather: agg[a][f] = sum_j m*lerp(tb,d)[f]*x1[j][f] ----
    {
      #pragma unroll 1
      for (int t = 0; t < 2; t++){
        int a = wv*2 + t;
        int f0 = lane, f1 = lane + 64;       // f1 in [64,127]; tbl 0 for >=100
        float agg0 = 0.0f, agg1 = 0.0f;
        #pragma unroll 1
        for (int j0 = 0; j0 < 32; j0 += 4){
          float w00[4], w01[4], w10[4], w11[4], frv[4], mv[4];
          #pragma unroll
          for (int u = 0; u < 4; u++){
            int j = j0 + u;
            float d = sD[a*33+j];            // wave-uniform broadcast
            mv[u] = sM[a*33+j];
            float un = d * (float)((G_TBL-1)/6.0);
            int s = (int)un;
            s = (s > G_TBL-2) ? (G_TBL-2) : s;
            frv[u] = un - (float)s;
            const float* rp = tb + s*TSTR;
            w00[u] = rp[f0]; w01[u] = rp[TSTR+f0];
            w10[u] = rp[f1]; w11[u] = rp[TSTR+f1];
          }
          #pragma unroll
          for (int u = 0; u < 4; u++){
            int j = j0 + u;
            float wa = w00[u] + frv[u]*(w01[u]-w00[u]);
            float wb = w10[u] + frv[u]*(w11[u]-w10[u]);
            agg0 += (mv[u]*wa) * sX1[j*X1STR + f0];
            agg1 += (mv[u]*wb) * sX1[j*X1STR + f1];
          }
        }
        sAf[a*136 + f0] = (_Float16)agg0;
        sAf[a*136 + f1] = (_Float16)agg1;    // f1>=100 -> exact 0 (tbl pad)
      }
    }
    __syncthreads();
    // ---- t2 = ssp(agg @ lin2 + b2l) -> sBf f16 ----
    for (int tau = wv; tau < 14; tau += NWAVES){
      int mt = tau/7, nt = tau - mt*7;
      f32x4 acc = {0.0f,0.0f,0.0f,0.0f};
      #pragma unroll
      for (int kc = 0; kc < 4; kc++){
        f16x8 a = *(const f16x8*)&sAf[(mt*16+n)*136 + kc*32 + q*8];
        f16x8 b = *(const f16x8*)&sWA[((kc*7+nt)*64 + lane)*8];
        acc = __builtin_amdgcn_mfma_f32_16x16x32_f16(a, b, acc, 0, 0, 0);
      }
      float bb = sB2l[nt*16+n];
      #pragma unroll
      for (int r = 0; r < 4; r++)
        sBf[(mt*16+q*4+r)*136 + nt*16+n] = (_Float16)sspf(acc[r] + bb);
    }
    __syncthreads();
    // ---- v = t2 @ lin + bl ; h += v  (linf staged at sWA+14336) ----
    for (int tau = wv; tau < 14; tau += NWAVES){
      int mt = tau/7, nt = tau - mt*7;
      f32x4 acc = {0.0f,0.0f,0.0f,0.0f};
      #pragma unroll
      for (int kc = 0; kc < 4; kc++){
        f16x8 a = *(const f16x8*)&sBf[(mt*16+n)*136 + kc*32 + q*8];
        f16x8 b = *(const f16x8*)&sWA[14336 + ((kc*7+nt)*64 + lane)*8];
        acc = __builtin_amdgcn_mfma_f32_16x16x32_f16(a, b, acc, 0, 0, 0);
      }
      int f = nt*16 + n;
      if (f < FEAT){
        float bb = sBlv[f];
        #pragma unroll
        for (int r = 0; r < 4; r++)
          sH[(mt*16+q*4+r)*NPAD + f] += acc[r] + bb;
      }
    }
    __syncthreads();
  }

  // ---------------- readout ----------------
  float* rw = (float*)sWA;                     // out_w1 [100][50] fp32
  for (int i = tid; i < 5000; i += NTHREADS) rw[i] = out_w1[i];
  if (tid < 50){ sB2l[tid] = out_b1[tid]; sBlv[tid] = out_w2[tid]; }
  __syncthreads();
  float ob2 = out_b2[0];
  float partial = 0.0f;
  for (int t = 0; t < 2; t++){
    int a = wv*2 + t;
    float u = 0.0f;
    if (lane < 50){
      u = sB2l[lane];
      #pragma unroll 4
      for (int c = 0; c < FEAT; c++)
        u += sH[a*NPAD + c] * rw[c*50 + lane];
      u = sspf(u) * sBlv[lane];
    }
    #pragma unroll
    for (int s = 1; s < 64; s <<= 1) u += __shfl_xor(u, s);
    partial += u + ob2;
  }
  if (lane == 0) sPart[wv] = partial;
  __syncthreads();
  if (tid == 0){
    float s = 0.0f;
    #pragma unroll
    for (int i = 0; i < NWAVES; i++) s += sPart[i];
    out[mol] = s;
  }
}

extern "C" void kernel_launch(void* const* d_in, const int* in_sizes, int n_in,
                              void* d_out, int out_size, void* d_ws, size_t ws_size,
                              hipStream_t stream)
{
  const int*   z      = (const int*)  d_in[0];
  const float* pos    = (const float*)d_in[1];
  /* d_in[2] = ptr: molecules are fixed 32-atom blocks; unused */
  const float* emb    = (const float*)d_in[3];
  const float* mlp_w1 = (const float*)d_in[4];
  const float* mlp_b1 = (const float*)d_in[5];
  const float* mlp_w2 = (const float*)d_in[6];
  const float* mlp_b2 = (const float*)d_in[7];
  const float* lin1_w = (const float*)d_in[8];
  const float* lin2_w = (const float*)d_in[9];
  const float* lin2_b = (const float*)d_in[10];
  const float* lin_w  = (const float*)d_in[11];
  const float* lin_b  = (const float*)d_in[12];
  const float* out_w1 = (const float*)d_in[13];
  const float* out_b1 = (const float*)d_in[14];
  const float* out_w2 = (const float*)d_in[15];
  const float* out_b2 = (const float*)d_in[16];

  _Float16* wfrag = (_Float16*)d_ws;                    // 344064 B
  float*    tbl   = (float*)((char*)d_ws + WTOTAL*2);   // 4*1024*128*4 = 2 MB

  prep_weights<<<WTOTAL/256, 256, 0, stream>>>(lin1_w, lin2_w, lin_w, wfrag);
  build_table<<<4*(G_TBL/4), 256, 0, stream>>>(mlp_w1, mlp_b1, mlp_w2, mlp_b2,
                                               tbl);
  schnet_mega<<<NMOL, NTHREADS, 0, stream>>>(z, pos, emb, wfrag, tbl,
      lin2_b, lin_b, out_w1, out_b1, out_w2, out_b2, (float*)d_out);
}